// Round 1
// baseline (717.288 us; speedup 1.0000x reference)
//
#include <hip/hip_runtime.h>

typedef unsigned short u16;
using bf16x8 = __attribute__((ext_vector_type(8))) __bf16;
using f32x4  = __attribute__((ext_vector_type(4))) float;

typedef const void __attribute__((address_space(1)))* gas1p;
typedef void __attribute__((address_space(3)))* las3p;

__device__ __forceinline__ void gload16(const void* g, void* l) {
  __builtin_amdgcn_global_load_lds((gas1p)g, (las3p)l, 16, 0, 0);
}

__device__ __forceinline__ u16 f2bf(float f) {
  union { float f; unsigned u; } v; v.f = f;
  unsigned r = v.u + 0x7FFFu + ((v.u >> 16) & 1u);
  return (u16)(r >> 16);
}
__device__ __forceinline__ float bf2f(u16 h) {
  union { unsigned u; float f; } v; v.u = ((unsigned)h) << 16;
  return v.f;
}

// ---------------- x fp32 -> bf16 ----------------
__global__ __launch_bounds__(256)
void cvt_f32_bf16(const float4* __restrict__ in, uint2* __restrict__ out, int n4) {
  int i = blockIdx.x * 256 + threadIdx.x;
  if (i >= n4) return;
  float4 v = in[i];
  uint2 o;
  o.x = (unsigned)f2bf(v.x) | ((unsigned)f2bf(v.y) << 16);
  o.y = (unsigned)f2bf(v.z) | ((unsigned)f2bf(v.w) << 16);
  out[i] = o;
}

// ---------------- W (R x C fp32) -> out (C x R bf16) ----------------
__global__ __launch_bounds__(256)
void transpose_w(const float* __restrict__ in, u16* __restrict__ out, int R, int C) {
  __shared__ float tile[32][33];
  const int tx = threadIdx.x & 31, ty = threadIdx.x >> 5;
  const int r0 = blockIdx.y * 32, c0 = blockIdx.x * 32;
#pragma unroll
  for (int i = 0; i < 4; i++)
    tile[ty + i * 8][tx] = in[(size_t)(r0 + ty + i * 8) * C + c0 + tx];
  __syncthreads();
#pragma unroll
  for (int i = 0; i < 4; i++)
    out[(size_t)(c0 + ty + i * 8) * R + r0 + tx] = f2bf(tile[tx][ty + i * 8]);
}

// ---------------- V slice of QKV -> Vt (b,kv,d,l) bf16 ----------------
__global__ __launch_bounds__(256)
void transpose_v(const u16* __restrict__ QKV, u16* __restrict__ Vt) {
  __shared__ u16 tile[32][34];
  const int tx = threadIdx.x & 31, ty = threadIdx.x >> 5;
  const int l0 = blockIdx.x * 32, d0 = blockIdx.y * 32;
  const int bkv = blockIdx.z;
  const int b = bkv >> 3, kvh = bkv & 7;
#pragma unroll
  for (int i = 0; i < 4; i++)
    tile[ty + i * 8][tx] =
        QKV[(size_t)(b * 2048 + l0 + ty + i * 8) * 6144 + 5120 + kvh * 128 + d0 + tx];
  __syncthreads();
#pragma unroll
  for (int i = 0; i < 4; i++)
    Vt[((size_t)bkv * 128 + d0 + ty + i * 8) * 2048 + l0 + tx] = tile[tx][ty + i * 8];
}

// ---------------- RMSNorm + RoPE (+1/sqrt(128) folded into Q) ----------------
__global__ __launch_bounds__(256)
void norm_rope(const u16* __restrict__ QKV, const float* __restrict__ qw,
               const float* __restrict__ kw, const float* __restrict__ cosp,
               const float* __restrict__ sinp, u16* __restrict__ Qr,
               u16* __restrict__ Kr) {
  const int rid = blockIdx.x * 4 + (threadIdx.x >> 6);
  const int lane = threadIdx.x & 63;
  const int head = rid % 40;
  const int bl = rid / 40;               // b*2048 + l
  const int b = bl >> 11, l = bl & 2047;
  const u16* src; const float* w; u16* dst; float scale;
  if (head < 32) {
    src = QKV + (size_t)bl * 6144 + head * 128;
    w = qw;
    dst = Qr + ((size_t)(b * 32 + head) * 2048 + l) * 128;
    scale = 0.08838834764831845f;        // 1/sqrt(128)
  } else {
    const int kvh = head - 32;
    src = QKV + (size_t)bl * 6144 + 4096 + kvh * 128;
    w = kw;
    dst = Kr + ((size_t)(b * 8 + kvh) * 2048 + l) * 128;
    scale = 1.0f;
  }
  float lo = bf2f(src[lane]);
  float hi = bf2f(src[lane + 64]);
  float ss = lo * lo + hi * hi;
#pragma unroll
  for (int m = 1; m < 64; m <<= 1) ss += __shfl_xor(ss, m, 64);
  const float rstd = rsqrtf(ss * (1.0f / 128.0f) + 1e-6f) * scale;
  const float nlo = lo * rstd * w[lane];
  const float nhi = hi * rstd * w[lane + 64];
  const float* cb = cosp + (size_t)bl * 128;
  const float* sb = sinp + (size_t)bl * 128;
  dst[lane]      = f2bf(nlo * cb[lane]      - nhi * sb[lane]);
  dst[lane + 64] = f2bf(nhi * cb[lane + 64] + nlo * sb[lane + 64]);
}

// ---------------- GEMM: C(MxN) = A(MxK) * Bt(NxK)^T, bf16 in, CT out --------
template <typename CT>
__global__ __launch_bounds__(256)
void gemm_bt(const u16* __restrict__ A, const u16* __restrict__ Bt,
             CT* __restrict__ C, int M, int N, int K) {
  __shared__ u16 As[128 * 32];
  __shared__ u16 Bs[128 * 32];
  const int tid = threadIdx.x;
  const int lane = tid & 63;
  const int wid = tid >> 6;
  const int wr = wid >> 1, wc = wid & 1;
  const int m0 = blockIdx.y * 128, n0 = blockIdx.x * 128;
  const int fr = lane & 15, fq = lane >> 4;

  f32x4 acc[4][4];
#pragma unroll
  for (int i = 0; i < 4; i++)
#pragma unroll
    for (int j = 0; j < 4; j++)
#pragma unroll
      for (int r = 0; r < 4; r++) acc[i][j][r] = 0.f;

  const int srow = tid >> 2;
  const int scol = (tid & 3) * 8;
  const u16* aptr = A + (size_t)(m0 + srow) * K + scol;
  const u16* bptr = Bt + (size_t)(n0 + srow) * K + scol;
  char* asd = (char*)As + tid * 16;
  char* bsd = (char*)Bs + tid * 16;
  const size_t r64 = (size_t)64 * K;

  for (int kk = 0; kk < K; kk += 32) {
    gload16(aptr + kk, asd);
    gload16(aptr + kk + r64, asd + 4096);
    gload16(bptr + kk, bsd);
    gload16(bptr + kk + r64, bsd + 4096);
    __syncthreads();
    bf16x8 af[4], bfr[4];
#pragma unroll
    for (int i = 0; i < 4; i++) {
      af[i]  = *(const bf16x8*)&As[(wr * 64 + i * 16 + fr) * 32 + fq * 8];
      bfr[i] = *(const bf16x8*)&Bs[(wc * 64 + i * 16 + fr) * 32 + fq * 8];
    }
#pragma unroll
    for (int i = 0; i < 4; i++)
#pragma unroll
      for (int j = 0; j < 4; j++)
        acc[i][j] = __builtin_amdgcn_mfma_f32_16x16x32_bf16(af[i], bfr[j], acc[i][j], 0, 0, 0);
    __syncthreads();
  }

#pragma unroll
  for (int i = 0; i < 4; i++) {
    const int row0 = m0 + wr * 64 + i * 16 + fq * 4;
#pragma unroll
    for (int j = 0; j < 4; j++) {
      const int col = n0 + wc * 64 + j * 16 + fr;
#pragma unroll
      for (int r = 0; r < 4; r++) {
        const size_t idx = (size_t)(row0 + r) * N + col;
        if constexpr (sizeof(CT) == 2) C[idx] = f2bf(acc[i][j][r]);
        else C[idx] = acc[i][j][r];
      }
    }
  }
}

// ---------------- Flash attention, causal GQA ----------------
// block: 256 thr = 4 waves; each wave: 16 q rows; KV tile = 64 keys.
__global__ __launch_bounds__(256)
void attn_fwd(const u16* __restrict__ Qr, const u16* __restrict__ Kr,
              const u16* __restrict__ Vt, u16* __restrict__ AO) {
  const int L = 2048, DH = 128;
  __shared__ u16 Ks[64 * 128];     // [key][d], XOR-swizzled
  __shared__ u16 Vs[128 * 64];     // [d][key], XOR-swizzled
  __shared__ u16 Pl[4][16][80];    // per-wave P, padded stride 160B
  const int tid = threadIdx.x, lane = tid & 63, wid = tid >> 6;
  const int fr = lane & 15, fq = lane >> 4;
  const int qt = blockIdx.x, h = blockIdx.y, b = blockIdx.z;
  const int kvh = h >> 2;
  const int q0 = qt * 64;
  const int qrow0 = q0 + wid * 16;

  const u16* qbase = Qr + ((size_t)(b * 32 + h) * L + qrow0 + fr) * DH + fq * 8;
  bf16x8 qf[4];
#pragma unroll
  for (int dt = 0; dt < 4; dt++) qf[dt] = *(const bf16x8*)(qbase + dt * 32);

  f32x4 o[8];
#pragma unroll
  for (int d = 0; d < 8; d++)
#pragma unroll
    for (int r = 0; r < 4; r++) o[d][r] = 0.f;
  float mrow[4], lrow[4];
#pragma unroll
  for (int r = 0; r < 4; r++) { mrow[r] = -__builtin_huge_valf(); lrow[r] = 0.f; }

  const u16* Kbase = Kr + (size_t)(b * 8 + kvh) * L * DH;
  const u16* Vbase = Vt + (size_t)(b * 8 + kvh) * DH * L;

  for (int kt = 0; kt <= qt; kt++) {
    const int k0 = kt * 64;
    // stage K tile (64 x 128) with XOR swizzle
#pragma unroll
    for (int p = 0; p < 4; p++) {
      const int idx = tid + p * 256;
      const int row = idx >> 4, c = idx & 15;
      uint4 v = *(const uint4*)(Kbase + (size_t)(k0 + row) * DH + c * 8);
      const int dst = (row * 256 + c * 16) ^ ((row & 7) << 4);
      *(uint4*)((char*)Ks + dst) = v;
    }
    // stage V tile (128 x 64) with XOR swizzle
#pragma unroll
    for (int p = 0; p < 4; p++) {
      const int idx = tid + p * 256;
      const int row = idx >> 3, c = idx & 7;
      uint4 v = *(const uint4*)(Vbase + (size_t)row * L + k0 + c * 8);
      const int dst = (row * 128 + c * 16) ^ ((row & 7) << 4);
      *(uint4*)((char*)Vs + dst) = v;
    }
    __syncthreads();

    // S = Q K^T  (scale pre-folded into Q)
    f32x4 s[4];
#pragma unroll
    for (int ni = 0; ni < 4; ni++)
#pragma unroll
      for (int r = 0; r < 4; r++) s[ni][r] = 0.f;
#pragma unroll
    for (int ni = 0; ni < 4; ni++) {
      const int krow = ni * 16 + fr;
      const int sw = (krow & 7) << 4;
#pragma unroll
      for (int dt = 0; dt < 4; dt++) {
        const int off = (krow * 256 + (dt * 32 + fq * 8) * 2) ^ sw;
        bf16x8 kf = *(const bf16x8*)((const char*)Ks + off);
        s[ni] = __builtin_amdgcn_mfma_f32_16x16x32_bf16(qf[dt], kf, s[ni], 0, 0, 0);
      }
    }

    if (kt == qt) {   // causal mask on the diagonal tile
#pragma unroll
      for (int ni = 0; ni < 4; ni++) {
        const int key = k0 + ni * 16 + fr;
#pragma unroll
        for (int r = 0; r < 4; r++)
          if (key > qrow0 + fq * 4 + r) s[ni][r] = -1e30f;
      }
    }

    // online softmax (rows live in regs r, cols across the 16-lane group)
    float corr[4], rs[4];
#pragma unroll
    for (int r = 0; r < 4; r++) {
      float m = fmaxf(fmaxf(s[0][r], s[1][r]), fmaxf(s[2][r], s[3][r]));
      m = fmaxf(m, __shfl_xor(m, 1, 64));
      m = fmaxf(m, __shfl_xor(m, 2, 64));
      m = fmaxf(m, __shfl_xor(m, 4, 64));
      m = fmaxf(m, __shfl_xor(m, 8, 64));
      const float mn = fmaxf(mrow[r], m);
      corr[r] = __expf(mrow[r] - mn);
      mrow[r] = mn;
      rs[r] = 0.f;
    }
#pragma unroll
    for (int ni = 0; ni < 4; ni++) {
#pragma unroll
      for (int r = 0; r < 4; r++) {
        const float p = __expf(s[ni][r] - mrow[r]);
        rs[r] += p;
        Pl[wid][fq * 4 + r][ni * 16 + fr] = f2bf(p);
      }
    }
#pragma unroll
    for (int r = 0; r < 4; r++) {
      float t = rs[r];
      t += __shfl_xor(t, 1, 64);
      t += __shfl_xor(t, 2, 64);
      t += __shfl_xor(t, 4, 64);
      t += __shfl_xor(t, 8, 64);
      lrow[r] = lrow[r] * corr[r] + t;
    }
#pragma unroll
    for (int d = 0; d < 8; d++)
#pragma unroll
      for (int r = 0; r < 4; r++) o[d][r] *= corr[r];

    // P fragments (A-operand layout) from per-wave LDS
    bf16x8 pa[2];
#pragma unroll
    for (int ks = 0; ks < 2; ks++)
      pa[ks] = *(const bf16x8*)&Pl[wid][fr][ks * 32 + fq * 8];

    // O += P V
#pragma unroll
    for (int d = 0; d < 8; d++) {
      const int vrow = d * 16 + fr;
      const int sw = (vrow & 7) << 4;
#pragma unroll
      for (int ks = 0; ks < 2; ks++) {
        const int off = (vrow * 128 + (ks * 32 + fq * 8) * 2) ^ sw;
        bf16x8 vf = *(const bf16x8*)((const char*)Vs + off);
        o[d] = __builtin_amdgcn_mfma_f32_16x16x32_bf16(pa[ks], vf, o[d], 0, 0, 0);
      }
    }
    __syncthreads();
  }

  float inv[4];
#pragma unroll
  for (int r = 0; r < 4; r++) inv[r] = 1.f / lrow[r];
#pragma unroll
  for (int d = 0; d < 8; d++) {
#pragma unroll
    for (int r = 0; r < 4; r++) {
      const size_t idx =
          ((size_t)b * L + qrow0 + fq * 4 + r) * 4096 + h * 128 + d * 16 + fr;
      AO[idx] = f2bf(o[d][r] * inv[r]);
    }
  }
}

// ---------------- launcher ----------------
extern "C" void kernel_launch(void* const* d_in, const int* in_sizes, int n_in,
                              void* d_out, int out_size, void* d_ws, size_t ws_size,
                              hipStream_t stream) {
  const float* x    = (const float*)d_in[0];
  const float* Wq   = (const float*)d_in[1];
  const float* Wk   = (const float*)d_in[2];
  const float* Wv   = (const float*)d_in[3];
  const float* Wo   = (const float*)d_in[4];
  const float* qw   = (const float*)d_in[5];
  const float* kw   = (const float*)d_in[6];
  const float* cosp = (const float*)d_in[7];
  const float* sinp = (const float*)d_in[8];
  float* out = (float*)d_out;
  char* ws = (char*)d_ws;

  // workspace layout (bytes), total 174,063,616
  u16* xb    = (u16*)(ws);                 // 4096x2560 bf16    (20,971,520)
  u16* WqkvT = (u16*)(ws + 20971520);      // 6144x2560 bf16    (31,457,280)
  u16* WoT   = (u16*)(ws + 52428800);      // 2560x4096 bf16    (20,971,520)
  u16* QKV   = (u16*)(ws + 73400320);      // 4096x6144 bf16    (50,331,648)
  u16* AO    = QKV;                        // alias: QKV dead before attn writes
  u16* Qrr   = (u16*)(ws + 123731968);     // (2,32,2048,128)   (33,554,432)
  u16* Krr   = (u16*)(ws + 157286400);     // (2,8,2048,128)    ( 8,388,608)
  u16* Vtt   = (u16*)(ws + 165675008);     // (2,8,128,2048)    ( 8,388,608)

  cvt_f32_bf16<<<10240, 256, 0, stream>>>((const float4*)x, (uint2*)xb, 2621440);
  transpose_w<<<dim3(128, 80), 256, 0, stream>>>(Wq, WqkvT, 2560, 4096);
  transpose_w<<<dim3(32, 80), 256, 0, stream>>>(Wk, WqkvT + (size_t)4096 * 2560, 2560, 1024);
  transpose_w<<<dim3(32, 80), 256, 0, stream>>>(Wv, WqkvT + (size_t)5120 * 2560, 2560, 1024);
  transpose_w<<<dim3(80, 128), 256, 0, stream>>>(Wo, WoT, 4096, 2560);

  gemm_bt<u16><<<dim3(48, 32), 256, 0, stream>>>(xb, WqkvT, QKV, 4096, 6144, 2560);

  norm_rope<<<40960, 256, 0, stream>>>(QKV, qw, kw, cosp, sinp, Qrr, Krr);
  transpose_v<<<dim3(64, 4, 16), 256, 0, stream>>>(QKV, Vtt);

  attn_fwd<<<dim3(32, 32, 2), 256, 0, stream>>>(Qrr, Krr, Vtt, AO);

  gemm_bt<float><<<dim3(20, 32), 256, 0, stream>>>(AO, WoT, out, 4096, 2560, 4096);
}

// Round 2
// 591.719 us; speedup vs baseline: 1.2122x; 1.2122x over previous
//
#include <hip/hip_runtime.h>

typedef unsigned short u16;
typedef unsigned int u32;
using bf16x8 = __attribute__((ext_vector_type(8))) __bf16;
using f32x4  = __attribute__((ext_vector_type(4))) float;

typedef const void __attribute__((address_space(1)))* gas1p;
typedef void __attribute__((address_space(3)))* las3p;

__device__ __forceinline__ void gload16(const void* g, void* l) {
  __builtin_amdgcn_global_load_lds((gas1p)g, (las3p)l, 16, 0, 0);
}

__device__ __forceinline__ u16 f2bf(float f) {
  union { float f; unsigned u; } v; v.f = f;
  unsigned r = v.u + 0x7FFFu + ((v.u >> 16) & 1u);
  return (u16)(r >> 16);
}
__device__ __forceinline__ float bf2f(u16 h) {
  union { unsigned u; float f; } v; v.u = ((unsigned)h) << 16;
  return v.f;
}

// ---------------- x fp32 -> bf16 ----------------
__global__ __launch_bounds__(256)
void cvt_f32_bf16(const float4* __restrict__ in, uint2* __restrict__ out, int n4) {
  int i = blockIdx.x * 256 + threadIdx.x;
  if (i >= n4) return;
  float4 v = in[i];
  uint2 o;
  o.x = (unsigned)f2bf(v.x) | ((unsigned)f2bf(v.y) << 16);
  o.y = (unsigned)f2bf(v.z) | ((unsigned)f2bf(v.w) << 16);
  out[i] = o;
}

// ---------------- W (R x C fp32) -> out (C x R bf16) ----------------
__global__ __launch_bounds__(256)
void transpose_w(const float* __restrict__ in, u16* __restrict__ out, int R, int C) {
  __shared__ float tile[32][33];
  const int tx = threadIdx.x & 31, ty = threadIdx.x >> 5;
  const int r0 = blockIdx.y * 32, c0 = blockIdx.x * 32;
#pragma unroll
  for (int i = 0; i < 4; i++)
    tile[ty + i * 8][tx] = in[(size_t)(r0 + ty + i * 8) * C + c0 + tx];
  __syncthreads();
#pragma unroll
  for (int i = 0; i < 4; i++)
    out[(size_t)(c0 + ty + i * 8) * R + r0 + tx] = f2bf(tile[tx][ty + i * 8]);
}

// ---------------- V slice of QKV -> Vt (b,kv,d,l) bf16 ----------------
__global__ __launch_bounds__(256)
void transpose_v(const u16* __restrict__ QKV, u16* __restrict__ Vt) {
  __shared__ u16 tile[32][34];
  const int tx = threadIdx.x & 31, ty = threadIdx.x >> 5;
  const int l0 = blockIdx.x * 32, d0 = blockIdx.y * 32;
  const int bkv = blockIdx.z;
  const int b = bkv >> 3, kvh = bkv & 7;
#pragma unroll
  for (int i = 0; i < 4; i++)
    tile[ty + i * 8][tx] =
        QKV[(size_t)(b * 2048 + l0 + ty + i * 8) * 6144 + 5120 + kvh * 128 + d0 + tx];
  __syncthreads();
#pragma unroll
  for (int i = 0; i < 4; i++)
    Vt[((size_t)bkv * 128 + d0 + ty + i * 8) * 2048 + l0 + tx] = tile[tx][ty + i * 8];
}

// ---------------- RMSNorm + RoPE (+1/sqrt(128) folded into Q) ----------------
__global__ __launch_bounds__(256)
void norm_rope(const u16* __restrict__ QKV, const float* __restrict__ qw,
               const float* __restrict__ kw, const float* __restrict__ cosp,
               const float* __restrict__ sinp, u16* __restrict__ Qr,
               u16* __restrict__ Kr) {
  const int rid = blockIdx.x * 4 + (threadIdx.x >> 6);
  const int lane = threadIdx.x & 63;
  const int head = rid % 40;
  const int bl = rid / 40;               // b*2048 + l
  const int b = bl >> 11, l = bl & 2047;
  const u16* src; const float* w; u16* dst; float scale;
  if (head < 32) {
    src = QKV + (size_t)bl * 6144 + head * 128;
    w = qw;
    dst = Qr + ((size_t)(b * 32 + head) * 2048 + l) * 128;
    scale = 0.08838834764831845f;        // 1/sqrt(128)
  } else {
    const int kvh = head - 32;
    src = QKV + (size_t)bl * 6144 + 4096 + kvh * 128;
    w = kw;
    dst = Kr + ((size_t)(b * 8 + kvh) * 2048 + l) * 128;
    scale = 1.0f;
  }
  float lo = bf2f(src[lane]);
  float hi = bf2f(src[lane + 64]);
  float ss = lo * lo + hi * hi;
#pragma unroll
  for (int m = 1; m < 64; m <<= 1) ss += __shfl_xor(ss, m, 64);
  const float rstd = rsqrtf(ss * (1.0f / 128.0f) + 1e-6f) * scale;
  const float nlo = lo * rstd * w[lane];
  const float nhi = hi * rstd * w[lane + 64];
  const float* cb = cosp + (size_t)bl * 128;
  const float* sb = sinp + (size_t)bl * 128;
  dst[lane]      = f2bf(nlo * cb[lane]      - nhi * sb[lane]);
  dst[lane + 64] = f2bf(nhi * cb[lane + 64] + nlo * sb[lane + 64]);
}

// ---------------- GEMM: C(MxN) = A(MxK) * Bt(NxK)^T, bf16 in, CT out --------
template <typename CT>
__global__ __launch_bounds__(256)
void gemm_bt(const u16* __restrict__ A, const u16* __restrict__ Bt,
             CT* __restrict__ C, int M, int N, int K) {
  __shared__ u16 As[128 * 32];
  __shared__ u16 Bs[128 * 32];
  const int tid = threadIdx.x;
  const int lane = tid & 63;
  const int wid = tid >> 6;
  const int wr = wid >> 1, wc = wid & 1;
  const int m0 = blockIdx.y * 128, n0 = blockIdx.x * 128;
  const int fr = lane & 15, fq = lane >> 4;

  f32x4 acc[4][4];
#pragma unroll
  for (int i = 0; i < 4; i++)
#pragma unroll
    for (int j = 0; j < 4; j++)
#pragma unroll
      for (int r = 0; r < 4; r++) acc[i][j][r] = 0.f;

  const int srow = tid >> 2;
  const int scol = (tid & 3) * 8;
  const u16* aptr = A + (size_t)(m0 + srow) * K + scol;
  const u16* bptr = Bt + (size_t)(n0 + srow) * K + scol;
  char* asd = (char*)As + tid * 16;
  char* bsd = (char*)Bs + tid * 16;
  const size_t r64 = (size_t)64 * K;

  for (int kk = 0; kk < K; kk += 32) {
    gload16(aptr + kk, asd);
    gload16(aptr + kk + r64, asd + 4096);
    gload16(bptr + kk, bsd);
    gload16(bptr + kk + r64, bsd + 4096);
    __syncthreads();
    bf16x8 af[4], bfr[4];
#pragma unroll
    for (int i = 0; i < 4; i++) {
      af[i]  = *(const bf16x8*)&As[(wr * 64 + i * 16 + fr) * 32 + fq * 8];
      bfr[i] = *(const bf16x8*)&Bs[(wc * 64 + i * 16 + fr) * 32 + fq * 8];
    }
#pragma unroll
    for (int i = 0; i < 4; i++)
#pragma unroll
      for (int j = 0; j < 4; j++)
        acc[i][j] = __builtin_amdgcn_mfma_f32_16x16x32_bf16(af[i], bfr[j], acc[i][j], 0, 0, 0);
    __syncthreads();
  }

#pragma unroll
  for (int i = 0; i < 4; i++) {
    const int row0 = m0 + wr * 64 + i * 16 + fq * 4;
#pragma unroll
    for (int j = 0; j < 4; j++) {
      const int col = n0 + wc * 64 + j * 16 + fr;
#pragma unroll
      for (int r = 0; r < 4; r++) {
        const size_t idx = (size_t)(row0 + r) * N + col;
        if constexpr (sizeof(CT) == 2) C[idx] = f2bf(acc[i][j][r]);
        else C[idx] = acc[i][j][r];
      }
    }
  }
}

// ---------------- Flash attention, causal GQA (swapped-operand S^T form) ----
// 4 waves/block, 16 q rows/wave, KV tile = 64 keys. LDS 32KB, no P round-trip.
__global__ __launch_bounds__(256, 4)
void attn_fwd(const u16* __restrict__ Qr, const u16* __restrict__ Kr,
              const u16* __restrict__ Vt, u16* __restrict__ AO) {
  const int L = 2048, DH = 128;
  __shared__ u16 Ks[64 * 128];     // [key][d], XOR-swizzled (^((row&7)<<4) on bytes)
  __shared__ u16 Vs[128 * 64];     // [d][key], XOR-swizzled
  const int tid = threadIdx.x, lane = tid & 63, wid = tid >> 6;
  const int fr = lane & 15, fq = lane >> 4;
  const int qt = (int)gridDim.x - 1 - (int)blockIdx.x;   // heavy blocks first
  const int h = blockIdx.y, b = blockIdx.z;
  const int kvh = h >> 2;
  const int q0 = qt * 64;
  const int qrow0 = q0 + wid * 16;
  const int q = qrow0 + fr;        // this lane's q row (S^T column)

  // Q as B-fragment: col=fr -> q, k = dt*32 + fq*8 + j
  const u16* qbase = Qr + ((size_t)(b * 32 + h) * L + q) * DH + fq * 8;
  bf16x8 qf[4];
#pragma unroll
  for (int dt = 0; dt < 4; dt++) qf[dt] = *(const bf16x8*)(qbase + dt * 32);

  f32x4 o[8];                      // O^T: row = d = dtile*16 + fq*4 + r, col = q
#pragma unroll
  for (int d = 0; d < 8; d++)
#pragma unroll
    for (int r = 0; r < 4; r++) o[d][r] = 0.f;
  float mrow = -__builtin_huge_valf(), lrow = 0.f;

  const u16* Kbase = Kr + (size_t)(b * 8 + kvh) * L * DH;
  const u16* Vbase = Vt + (size_t)(b * 8 + kvh) * DH * L;

  // pre-swizzled staging offsets: LDS dest is linear (tid+p*256)*16 bytes,
  // global source address carries the inverse swizzle (m173 pattern).
  int Dly[4], kOff[4], vOff[4];
#pragma unroll
  for (int p = 0; p < 4; p++) {
    const int D = (tid + p * 256) * 16;
    Dly[p] = D;
    const int kr = D >> 8, kc = ((D >> 4) & 15) ^ (kr & 7);
    kOff[p] = kr * 128 + kc * 8;               // elements
    const int vr = D >> 7, vc = ((D >> 4) & 7) ^ (vr & 7);
    vOff[p] = vr * 2048 + vc * 8;              // elements
  }

  const bool B5 = (lane & 32) != 0;
  const bool A4 = (lane & 16) != 0;

  for (int kt = 0; kt <= qt; kt++) {
    const int k0 = kt * 64;
    __syncthreads();               // previous tile's LDS reads done
#pragma unroll
    for (int p = 0; p < 4; p++) {
      gload16(Kbase + (size_t)k0 * 128 + kOff[p], (char*)Ks + Dly[p]);
      gload16(Vbase + k0 + vOff[p], (char*)Vs + Dly[p]);
    }
    __syncthreads();               // staged (compiler drains vmcnt)

    // S^T = K Q^T : s4[ni][r] = S[q][key=k0+ni*16+fq*4+r]
    f32x4 s4[4];
#pragma unroll
    for (int ni = 0; ni < 4; ni++)
#pragma unroll
      for (int r = 0; r < 4; r++) s4[ni][r] = 0.f;
#pragma unroll
    for (int ni = 0; ni < 4; ni++) {
      const int krow = ni * 16 + fr;
      const int sw = (krow & 7) << 4;
#pragma unroll
      for (int dt = 0; dt < 4; dt++) {
        const int off = (krow * 256 + dt * 64 + fq * 16) ^ sw;
        bf16x8 kf = *(const bf16x8*)((const char*)Ks + off);
        s4[ni] = __builtin_amdgcn_mfma_f32_16x16x32_bf16(kf, qf[dt], s4[ni], 0, 0, 0);
      }
    }

    if (kt == qt) {                // causal mask on diagonal tile
#pragma unroll
      for (int ni = 0; ni < 4; ni++) {
#pragma unroll
        for (int r = 0; r < 4; r++)
          if (k0 + ni * 16 + fq * 4 + r > q) s4[ni][r] = -1e30f;
      }
    }

    // tile max (reduce over keys: in-lane 16 + fq-group shuffles)
    float mt = s4[0][0];
#pragma unroll
    for (int ni = 0; ni < 4; ni++)
#pragma unroll
      for (int r = 0; r < 4; r++) mt = fmaxf(mt, s4[ni][r]);
    mt = fmaxf(mt, __shfl_xor(mt, 16, 64));
    mt = fmaxf(mt, __shfl_xor(mt, 32, 64));

    if (!__all(mt <= mrow + 8.f)) {          // defer-max (T13)
      const float mn = fmaxf(mrow, mt);
      const float corr = exp2f((mrow - mn) * 1.44269504f);
      mrow = mn;
      lrow *= corr;
#pragma unroll
      for (int d = 0; d < 8; d++)
#pragma unroll
        for (int r = 0; r < 4; r++) o[d][r] *= corr;
    }

    // P = exp(S - mrow), row-sum, pack to bf16 pairs
    const float ml = mrow * 1.44269504f;
    float rs = 0.f;
#pragma unroll
    for (int ni = 0; ni < 4; ni++)
#pragma unroll
      for (int r = 0; r < 4; r++) {
        const float pv = exp2f(fmaf(s4[ni][r], 1.44269504f, -ml));
        s4[ni][r] = pv;
        rs += pv;
      }
    rs += __shfl_xor(rs, 16, 64);
    rs += __shfl_xor(rs, 32, 64);
    lrow += rs;

    u32 pk[4][2];
#pragma unroll
    for (int ni = 0; ni < 4; ni++) {
      pk[ni][0] = __builtin_amdgcn_perm(__float_as_uint(s4[ni][1]),
                                        __float_as_uint(s4[ni][0]), 0x07060302u);
      pk[ni][1] = __builtin_amdgcn_perm(__float_as_uint(s4[ni][3]),
                                        __float_as_uint(s4[ni][2]), 0x07060302u);
    }

    // PV: O^T += V^T * P^T ; P^T B-frag built by two lane-bit<->reg-bit swaps
#pragma unroll
    for (int ks = 0; ks < 2; ks++) {
      u32 r00 = pk[2 * ks + 0][0], r01 = pk[2 * ks + 0][1];
      u32 r10 = pk[2 * ks + 1][0], r11 = pk[2 * ks + 1][1];
      // T1: swap lane bit5 with reg index u
      u32 e0 = __shfl_xor(B5 ? r00 : r10, 32, 64);
      u32 t00 = B5 ? e0 : r00, t10 = B5 ? r10 : e0;
      u32 e1 = __shfl_xor(B5 ? r01 : r11, 32, 64);
      u32 t01 = B5 ? e1 : r01, t11 = B5 ? r11 : e1;
      // T2: swap lane bit4 with reg index u
      u32 e2 = __shfl_xor(A4 ? t00 : t10, 16, 64);
      u32 u00 = A4 ? e2 : t00, u10 = A4 ? t10 : e2;
      u32 e3 = __shfl_xor(A4 ? t01 : t11, 16, 64);
      u32 u01 = A4 ? e3 : t01, u11 = A4 ? t11 : e3;
      union { u32 u[4]; bf16x8 v; } pb;
      pb.u[0] = u00; pb.u[1] = u01; pb.u[2] = u10; pb.u[3] = u11;
#pragma unroll
      for (int d = 0; d < 8; d++) {
        const int vrow = d * 16 + fr;
        const int sw = (vrow & 7) << 4;
        const int off = (vrow * 128 + ks * 64 + fq * 16) ^ sw;
        bf16x8 vf = *(const bf16x8*)((const char*)Vs + off);
        o[d] = __builtin_amdgcn_mfma_f32_16x16x32_bf16(vf, pb.v, o[d], 0, 0, 0);
      }
    }
  }

  const float inv = 1.f / lrow;
  u16* obase = AO + ((size_t)b * L + q) * 4096 + h * 128 + fq * 4;
#pragma unroll
  for (int d = 0; d < 8; d++) {
    uint2 w;
    w.x = (u32)f2bf(o[d][0] * inv) | ((u32)f2bf(o[d][1] * inv) << 16);
    w.y = (u32)f2bf(o[d][2] * inv) | ((u32)f2bf(o[d][3] * inv) << 16);
    *(uint2*)(obase + d * 16) = w;
  }
}

// ---------------- launcher ----------------
extern "C" void kernel_launch(void* const* d_in, const int* in_sizes, int n_in,
                              void* d_out, int out_size, void* d_ws, size_t ws_size,
                              hipStream_t stream) {
  const float* x    = (const float*)d_in[0];
  const float* Wq   = (const float*)d_in[1];
  const float* Wk   = (const float*)d_in[2];
  const float* Wv   = (const float*)d_in[3];
  const float* Wo   = (const float*)d_in[4];
  const float* qw   = (const float*)d_in[5];
  const float* kw   = (const float*)d_in[6];
  const float* cosp = (const float*)d_in[7];
  const float* sinp = (const float*)d_in[8];
  float* out = (float*)d_out;
  char* ws = (char*)d_ws;

  // workspace layout (bytes), total 174,063,616
  u16* xb    = (u16*)(ws);                 // 4096x2560 bf16    (20,971,520)
  u16* WqkvT = (u16*)(ws + 20971520);      // 6144x2560 bf16    (31,457,280)
  u16* WoT   = (u16*)(ws + 52428800);      // 2560x4096 bf16    (20,971,520)
  u16* QKV   = (u16*)(ws + 73400320);      // 4096x6144 bf16    (50,331,648)
  u16* AO    = QKV;                        // alias: QKV dead before attn writes
  u16* Qrr   = (u16*)(ws + 123731968);     // (2,32,2048,128)   (33,554,432)
  u16* Krr   = (u16*)(ws + 157286400);     // (2,8,2048,128)    ( 8,388,608)
  u16* Vtt   = (u16*)(ws + 165675008);     // (2,8,128,2048)    ( 8,388,608)

  cvt_f32_bf16<<<10240, 256, 0, stream>>>((const float4*)x, (uint2*)xb, 2621440);
  transpose_w<<<dim3(128, 80), 256, 0, stream>>>(Wq, WqkvT, 2560, 4096);
  transpose_w<<<dim3(32, 80), 256, 0, stream>>>(Wk, WqkvT + (size_t)4096 * 2560, 2560, 1024);
  transpose_w<<<dim3(32, 80), 256, 0, stream>>>(Wv, WqkvT + (size_t)5120 * 2560, 2560, 1024);
  transpose_w<<<dim3(80, 128), 256, 0, stream>>>(Wo, WoT, 4096, 2560);

  gemm_bt<u16><<<dim3(48, 32), 256, 0, stream>>>(xb, WqkvT, QKV, 4096, 6144, 2560);

  norm_rope<<<40960, 256, 0, stream>>>(QKV, qw, kw, cosp, sinp, Qrr, Krr);
  transpose_v<<<dim3(64, 4, 16), 256, 0, stream>>>(QKV, Vtt);

  attn_fwd<<<dim3(32, 32, 2), 256, 0, stream>>>(Qrr, Krr, Vtt, AO);

  gemm_bt<float><<<dim3(20, 32), 256, 0, stream>>>(AO, WoT, out, 4096, 2560, 4096);
}

// Round 3
// 518.714 us; speedup vs baseline: 1.3828x; 1.1407x over previous
//
#include <hip/hip_runtime.h>

typedef unsigned short u16;
typedef unsigned int u32;
using bf16x8 = __attribute__((ext_vector_type(8))) __bf16;
using f32x4  = __attribute__((ext_vector_type(4))) float;

typedef const void __attribute__((address_space(1)))* gas1p;
typedef void __attribute__((address_space(3)))* las3p;

__device__ __forceinline__ void gload16(const void* g, void* l) {
  __builtin_amdgcn_global_load_lds((gas1p)g, (las3p)l, 16, 0, 0);
}

__device__ __forceinline__ u16 f2bf(float f) {
  union { float f; unsigned u; } v; v.f = f;
  unsigned r = v.u + 0x7FFFu + ((v.u >> 16) & 1u);
  return (u16)(r >> 16);
}
__device__ __forceinline__ float bf2f(u16 h) {
  union { unsigned u; float f; } v; v.u = ((unsigned)h) << 16;
  return v.f;
}

// ---------------- x fp32 -> bf16 ----------------
__global__ __launch_bounds__(256)
void cvt_f32_bf16(const float4* __restrict__ in, uint2* __restrict__ out, int n4) {
  int i = blockIdx.x * 256 + threadIdx.x;
  if (i >= n4) return;
  float4 v = in[i];
  uint2 o;
  o.x = (unsigned)f2bf(v.x) | ((unsigned)f2bf(v.y) << 16);
  o.y = (unsigned)f2bf(v.z) | ((unsigned)f2bf(v.w) << 16);
  out[i] = o;
}

// ---------------- W (R x C fp32) -> out (C x R bf16) ----------------
__global__ __launch_bounds__(256)
void transpose_w(const float* __restrict__ in, u16* __restrict__ out, int R, int C) {
  __shared__ float tile[32][33];
  const int tx = threadIdx.x & 31, ty = threadIdx.x >> 5;
  const int r0 = blockIdx.y * 32, c0 = blockIdx.x * 32;
#pragma unroll
  for (int i = 0; i < 4; i++)
    tile[ty + i * 8][tx] = in[(size_t)(r0 + ty + i * 8) * C + c0 + tx];
  __syncthreads();
#pragma unroll
  for (int i = 0; i < 4; i++)
    out[(size_t)(c0 + ty + i * 8) * R + r0 + tx] = f2bf(tile[tx][ty + i * 8]);
}

// ---------------- V slice of QKV -> Vt (b,kv,d,l) bf16 ----------------
__global__ __launch_bounds__(256)
void transpose_v(const u16* __restrict__ QKV, u16* __restrict__ Vt) {
  __shared__ u16 tile[32][34];
  const int tx = threadIdx.x & 31, ty = threadIdx.x >> 5;
  const int l0 = blockIdx.x * 32, d0 = blockIdx.y * 32;
  const int bkv = blockIdx.z;
  const int b = bkv >> 3, kvh = bkv & 7;
#pragma unroll
  for (int i = 0; i < 4; i++)
    tile[ty + i * 8][tx] =
        QKV[(size_t)(b * 2048 + l0 + ty + i * 8) * 6144 + 5120 + kvh * 128 + d0 + tx];
  __syncthreads();
#pragma unroll
  for (int i = 0; i < 4; i++)
    Vt[((size_t)bkv * 128 + d0 + ty + i * 8) * 2048 + l0 + tx] = tile[tx][ty + i * 8];
}

// ---------------- RMSNorm + RoPE (+1/sqrt(128) folded into Q) ----------------
__global__ __launch_bounds__(256)
void norm_rope(const u16* __restrict__ QKV, const float* __restrict__ qw,
               const float* __restrict__ kw, const float* __restrict__ cosp,
               const float* __restrict__ sinp, u16* __restrict__ Qr,
               u16* __restrict__ Kr) {
  const int rid = blockIdx.x * 4 + (threadIdx.x >> 6);
  const int lane = threadIdx.x & 63;
  const int head = rid % 40;
  const int bl = rid / 40;               // b*2048 + l
  const int b = bl >> 11, l = bl & 2047;
  const u16* src; const float* w; u16* dst; float scale;
  if (head < 32) {
    src = QKV + (size_t)bl * 6144 + head * 128;
    w = qw;
    dst = Qr + ((size_t)(b * 32 + head) * 2048 + l) * 128;
    scale = 0.08838834764831845f;        // 1/sqrt(128)
  } else {
    const int kvh = head - 32;
    src = QKV + (size_t)bl * 6144 + 4096 + kvh * 128;
    w = kw;
    dst = Kr + ((size_t)(b * 8 + kvh) * 2048 + l) * 128;
    scale = 1.0f;
  }
  float lo = bf2f(src[lane]);
  float hi = bf2f(src[lane + 64]);
  float ss = lo * lo + hi * hi;
#pragma unroll
  for (int m = 1; m < 64; m <<= 1) ss += __shfl_xor(ss, m, 64);
  const float rstd = rsqrtf(ss * (1.0f / 128.0f) + 1e-6f) * scale;
  const float nlo = lo * rstd * w[lane];
  const float nhi = hi * rstd * w[lane + 64];
  const float* cb = cosp + (size_t)bl * 128;
  const float* sb = sinp + (size_t)bl * 128;
  dst[lane]      = f2bf(nlo * cb[lane]      - nhi * sb[lane]);
  dst[lane + 64] = f2bf(nhi * cb[lane + 64] + nlo * sb[lane + 64]);
}

// ---------------- GEMM: C(MxN) = A(MxK) * Bt(NxK)^T, bf16 in, CT out --------
template <typename CT>
__global__ __launch_bounds__(256)
void gemm_bt(const u16* __restrict__ A, const u16* __restrict__ Bt,
             CT* __restrict__ C, int M, int N, int K) {
  __shared__ u16 As[128 * 32];
  __shared__ u16 Bs[128 * 32];
  const int tid = threadIdx.x;
  const int lane = tid & 63;
  const int wid = tid >> 6;
  const int wr = wid >> 1, wc = wid & 1;
  const int m0 = blockIdx.y * 128, n0 = blockIdx.x * 128;
  const int fr = lane & 15, fq = lane >> 4;

  f32x4 acc[4][4];
#pragma unroll
  for (int i = 0; i < 4; i++)
#pragma unroll
    for (int j = 0; j < 4; j++)
#pragma unroll
      for (int r = 0; r < 4; r++) acc[i][j][r] = 0.f;

  const int srow = tid >> 2;
  const int scol = (tid & 3) * 8;
  const u16* aptr = A + (size_t)(m0 + srow) * K + scol;
  const u16* bptr = Bt + (size_t)(n0 + srow) * K + scol;
  char* asd = (char*)As + tid * 16;
  char* bsd = (char*)Bs + tid * 16;
  const size_t r64 = (size_t)64 * K;

  for (int kk = 0; kk < K; kk += 32) {
    gload16(aptr + kk, asd);
    gload16(aptr + kk + r64, asd + 4096);
    gload16(bptr + kk, bsd);
    gload16(bptr + kk + r64, bsd + 4096);
    __syncthreads();
    bf16x8 af[4], bfr[4];
#pragma unroll
    for (int i = 0; i < 4; i++) {
      af[i]  = *(const bf16x8*)&As[(wr * 64 + i * 16 + fr) * 32 + fq * 8];
      bfr[i] = *(const bf16x8*)&Bs[(wc * 64 + i * 16 + fr) * 32 + fq * 8];
    }
#pragma unroll
    for (int i = 0; i < 4; i++)
#pragma unroll
      for (int j = 0; j < 4; j++)
        acc[i][j] = __builtin_amdgcn_mfma_f32_16x16x32_bf16(af[i], bfr[j], acc[i][j], 0, 0, 0);
    __syncthreads();
  }

#pragma unroll
  for (int i = 0; i < 4; i++) {
    const int row0 = m0 + wr * 64 + i * 16 + fq * 4;
#pragma unroll
    for (int j = 0; j < 4; j++) {
      const int col = n0 + wc * 64 + j * 16 + fr;
#pragma unroll
      for (int r = 0; r < 4; r++) {
        const size_t idx = (size_t)(row0 + r) * N + col;
        if constexpr (sizeof(CT) == 2) C[idx] = f2bf(acc[i][j][r]);
        else C[idx] = acc[i][j][r];
      }
    }
  }
}

// ---------------- Flash attention, causal GQA ----------------
// Block = one kv-group: 4 waves = 4 q-heads sharing K/V. Each wave: 32 q rows
// (2 col-groups). Q-tile pair (j, 63-j) => every block exactly 33 kv-steps.
// Double-buffered K/V staging, counted vmcnt(8), raw barriers (T3/T4).
__global__ __launch_bounds__(256, 2)
void attn_fwd(const u16* __restrict__ Qr, const u16* __restrict__ Kr,
              const u16* __restrict__ Vt, u16* __restrict__ AO) {
  const int L = 2048, DH = 128;
  __shared__ u16 Ks[2][64 * 128];   // [buf][key][d], XOR-swizzled
  __shared__ u16 Vs[2][128 * 64];   // [buf][d][key], XOR-swizzled
  const int tid = threadIdx.x, lane = tid & 63, wid = tid >> 6;
  const int fr = lane & 15, fq = lane >> 4;
  // XCD-friendly decode: blocks sharing K/V have blockIdx.x = const (mod 16)
  const int j = blockIdx.x >> 4;           // q-tile pair index [0,32)
  const int grp = blockIdx.x & 15;
  const int kvh = grp >> 1, b = grp & 1;
  const int h = kvh * 4 + wid;

  const u16* Kbase = Kr + (size_t)(b * 8 + kvh) * L * DH;
  const u16* Vbase = Vt + (size_t)(b * 8 + kvh) * DH * L;

  // pre-swizzled staging offsets (LDS dest linear, source carries inverse swizzle)
  int Dly[4], kOff[4], vOff[4];
#pragma unroll
  for (int p = 0; p < 4; p++) {
    const int D = (tid + p * 256) * 16;
    Dly[p] = D;
    const int kr = D >> 8, kc = ((D >> 4) & 15) ^ (kr & 7);
    kOff[p] = kr * 128 + kc * 8;
    const int vr = D >> 7, vc = ((D >> 4) & 7) ^ (vr & 7);
    vOff[p] = vr * 2048 + vc * 8;
  }

  const bool B5 = (lane & 32) != 0;
  const bool A4 = (lane & 16) != 0;

  auto stage = [&](int kt, int bufi) {
    const int k0 = kt * 64;
#pragma unroll
    for (int p = 0; p < 4; p++) {
      gload16(Kbase + (size_t)k0 * 128 + kOff[p], (char*)&Ks[bufi][0] + Dly[p]);
      gload16(Vbase + k0 + vOff[p], (char*)&Vs[bufi][0] + Dly[p]);
    }
  };

  for (int half = 0; half < 2; half++) {
    const int t = half ? 63 - j : j;         // 32-row q-tile index [0,64)
    const int nk = (t >> 1) + 1;             // kv tiles of 64 keys

    // Q fragments for both col-groups (q = t*32 + g*16 + fr)
    bf16x8 qf[2][4];
#pragma unroll
    for (int g = 0; g < 2; g++) {
      const int q = t * 32 + g * 16 + fr;
      const u16* qbase = Qr + ((size_t)(b * 32 + h) * L + q) * DH + fq * 8;
#pragma unroll
      for (int dt = 0; dt < 4; dt++) qf[g][dt] = *(const bf16x8*)(qbase + dt * 32);
    }
    asm volatile("s_waitcnt vmcnt(0)" ::: "memory");  // clean vm counter

    f32x4 o[2][8];
#pragma unroll
    for (int g = 0; g < 2; g++)
#pragma unroll
      for (int d = 0; d < 8; d++)
#pragma unroll
        for (int r = 0; r < 4; r++) o[g][d][r] = 0.f;
    float mrow[2] = {-__builtin_huge_valf(), -__builtin_huge_valf()};
    float lrow[2] = {0.f, 0.f};

    __builtin_amdgcn_s_barrier();   // prior pass finished reading LDS
    stage(0, 0);
    int cur = 0;

    for (int kt = 0; kt < nk; kt++) {
      if (kt + 1 < nk) {
        stage(kt + 1, cur ^ 1);
        asm volatile("s_waitcnt vmcnt(8)" ::: "memory");  // tile kt staged
      } else {
        asm volatile("s_waitcnt vmcnt(0)" ::: "memory");
      }
      __builtin_amdgcn_s_barrier();

      const u16* KsB = &Ks[cur][0];
      const u16* VsB = &Vs[cur][0];
      const int k0 = kt * 64;

      // S^T = K Q^T for both groups, sharing each K fragment
      f32x4 s4[2][4];
#pragma unroll
      for (int g = 0; g < 2; g++)
#pragma unroll
        for (int ni = 0; ni < 4; ni++)
#pragma unroll
          for (int r = 0; r < 4; r++) s4[g][ni][r] = 0.f;
#pragma unroll
      for (int ni = 0; ni < 4; ni++) {
        const int krow = ni * 16 + fr;
        const int sw = (krow & 7) << 4;
#pragma unroll
        for (int dt = 0; dt < 4; dt++) {
          const int off = (krow * 256 + dt * 64 + fq * 16) ^ sw;
          bf16x8 kf = *(const bf16x8*)((const char*)KsB + off);
          s4[0][ni] = __builtin_amdgcn_mfma_f32_16x16x32_bf16(kf, qf[0][dt], s4[0][ni], 0, 0, 0);
          s4[1][ni] = __builtin_amdgcn_mfma_f32_16x16x32_bf16(kf, qf[1][dt], s4[1][ni], 0, 0, 0);
        }
      }

      if (kt == nk - 1) {           // causal mask on the diagonal tile
#pragma unroll
        for (int g = 0; g < 2; g++) {
          const int q = t * 32 + g * 16 + fr;
#pragma unroll
          for (int ni = 0; ni < 4; ni++)
#pragma unroll
            for (int r = 0; r < 4; r++)
              if (k0 + ni * 16 + fq * 4 + r > q) s4[g][ni][r] = -1e30f;
        }
      }

      // per-group online softmax + pack + in-register transpose
      bf16x8 pb[2][2];
#pragma unroll
      for (int g = 0; g < 2; g++) {
        float mt = s4[g][0][0];
#pragma unroll
        for (int ni = 0; ni < 4; ni++)
#pragma unroll
          for (int r = 0; r < 4; r++) mt = fmaxf(mt, s4[g][ni][r]);
        mt = fmaxf(mt, __shfl_xor(mt, 16, 64));
        mt = fmaxf(mt, __shfl_xor(mt, 32, 64));

        if (!__all(mt <= mrow[g] + 8.f)) {   // defer-max (T13)
          const float mn = fmaxf(mrow[g], mt);
          const float corr = exp2f((mrow[g] - mn) * 1.44269504f);
          mrow[g] = mn;
          lrow[g] *= corr;
#pragma unroll
          for (int d = 0; d < 8; d++)
#pragma unroll
            for (int r = 0; r < 4; r++) o[g][d][r] *= corr;
        }

        const float ml = mrow[g] * 1.44269504f;
        float rs = 0.f;
#pragma unroll
        for (int ni = 0; ni < 4; ni++)
#pragma unroll
          for (int r = 0; r < 4; r++) {
            const float pv = exp2f(fmaf(s4[g][ni][r], 1.44269504f, -ml));
            s4[g][ni][r] = pv;
            rs += pv;
          }
        rs += __shfl_xor(rs, 16, 64);
        rs += __shfl_xor(rs, 32, 64);
        lrow[g] += rs;

        u32 pk[4][2];
#pragma unroll
        for (int ni = 0; ni < 4; ni++) {
          pk[ni][0] = __builtin_amdgcn_perm(__float_as_uint(s4[g][ni][1]),
                                            __float_as_uint(s4[g][ni][0]), 0x07060302u);
          pk[ni][1] = __builtin_amdgcn_perm(__float_as_uint(s4[g][ni][3]),
                                            __float_as_uint(s4[g][ni][2]), 0x07060302u);
        }
#pragma unroll
        for (int ks = 0; ks < 2; ks++) {
          u32 r00 = pk[2 * ks + 0][0], r01 = pk[2 * ks + 0][1];
          u32 r10 = pk[2 * ks + 1][0], r11 = pk[2 * ks + 1][1];
          u32 e0 = __shfl_xor(B5 ? r00 : r10, 32, 64);
          u32 t00 = B5 ? e0 : r00, t10 = B5 ? r10 : e0;
          u32 e1 = __shfl_xor(B5 ? r01 : r11, 32, 64);
          u32 t01 = B5 ? e1 : r01, t11 = B5 ? r11 : e1;
          u32 e2 = __shfl_xor(A4 ? t00 : t10, 16, 64);
          u32 u00 = A4 ? e2 : t00, u10 = A4 ? t10 : e2;
          u32 e3 = __shfl_xor(A4 ? t01 : t11, 16, 64);
          u32 u01 = A4 ? e3 : t01, u11 = A4 ? t11 : e3;
          union { u32 u[4]; bf16x8 v; } pbv;
          pbv.u[0] = u00; pbv.u[1] = u01; pbv.u[2] = u10; pbv.u[3] = u11;
          pb[g][ks] = pbv.v;
        }
      }

      // O^T += V^T P^T for both groups, sharing each V fragment
#pragma unroll
      for (int d = 0; d < 8; d++) {
        const int vrow = d * 16 + fr;
        const int sw = (vrow & 7) << 4;
#pragma unroll
        for (int ks = 0; ks < 2; ks++) {
          const int off = (vrow * 128 + ks * 64 + fq * 16) ^ sw;
          bf16x8 vf = *(const bf16x8*)((const char*)VsB + off);
          o[0][d] = __builtin_amdgcn_mfma_f32_16x16x32_bf16(vf, pb[0][ks], o[0][d], 0, 0, 0);
          o[1][d] = __builtin_amdgcn_mfma_f32_16x16x32_bf16(vf, pb[1][ks], o[1][d], 0, 0, 0);
        }
      }
      __builtin_amdgcn_s_barrier();   // all waves done reading buf[cur]
      cur ^= 1;
    }

    // epilogue: normalize and store O^T
#pragma unroll
    for (int g = 0; g < 2; g++) {
      const float inv = 1.f / lrow[g];
      const int q = t * 32 + g * 16 + fr;
      u16* obase = AO + ((size_t)b * L + q) * 4096 + h * 128 + fq * 4;
#pragma unroll
      for (int d = 0; d < 8; d++) {
        uint2 w;
        w.x = (u32)f2bf(o[g][d][0] * inv) | ((u32)f2bf(o[g][d][1] * inv) << 16);
        w.y = (u32)f2bf(o[g][d][2] * inv) | ((u32)f2bf(o[g][d][3] * inv) << 16);
        *(uint2*)(obase + d * 16) = w;
      }
    }
  }
}

// ---------------- launcher ----------------
extern "C" void kernel_launch(void* const* d_in, const int* in_sizes, int n_in,
                              void* d_out, int out_size, void* d_ws, size_t ws_size,
                              hipStream_t stream) {
  const float* x    = (const float*)d_in[0];
  const float* Wq   = (const float*)d_in[1];
  const float* Wk   = (const float*)d_in[2];
  const float* Wv   = (const float*)d_in[3];
  const float* Wo   = (const float*)d_in[4];
  const float* qw   = (const float*)d_in[5];
  const float* kw   = (const float*)d_in[6];
  const float* cosp = (const float*)d_in[7];
  const float* sinp = (const float*)d_in[8];
  float* out = (float*)d_out;
  char* ws = (char*)d_ws;

  // workspace layout (bytes), total 174,063,616
  u16* xb    = (u16*)(ws);                 // 4096x2560 bf16    (20,971,520)
  u16* WqkvT = (u16*)(ws + 20971520);      // 6144x2560 bf16    (31,457,280)
  u16* WoT   = (u16*)(ws + 52428800);      // 2560x4096 bf16    (20,971,520)
  u16* QKV   = (u16*)(ws + 73400320);      // 4096x6144 bf16    (50,331,648)
  u16* AO    = QKV;                        // alias: QKV dead before attn writes
  u16* Qrr   = (u16*)(ws + 123731968);     // (2,32,2048,128)   (33,554,432)
  u16* Krr   = (u16*)(ws + 157286400);     // (2,8,2048,128)    ( 8,388,608)
  u16* Vtt   = (u16*)(ws + 165675008);     // (2,8,128,2048)    ( 8,388,608)

  cvt_f32_bf16<<<10240, 256, 0, stream>>>((const float4*)x, (uint2*)xb, 2621440);
  transpose_w<<<dim3(128, 80), 256, 0, stream>>>(Wq, WqkvT, 2560, 4096);
  transpose_w<<<dim3(32, 80), 256, 0, stream>>>(Wk, WqkvT + (size_t)4096 * 2560, 2560, 1024);
  transpose_w<<<dim3(32, 80), 256, 0, stream>>>(Wv, WqkvT + (size_t)5120 * 2560, 2560, 1024);
  transpose_w<<<dim3(80, 128), 256, 0, stream>>>(Wo, WoT, 4096, 2560);

  gemm_bt<u16><<<dim3(48, 32), 256, 0, stream>>>(xb, WqkvT, QKV, 4096, 6144, 2560);

  norm_rope<<<40960, 256, 0, stream>>>(QKV, qw, kw, cosp, sinp, Qrr, Krr);
  transpose_v<<<dim3(64, 4, 16), 256, 0, stream>>>(QKV, Vtt);

  attn_fwd<<<dim3(512), 256, 0, stream>>>(Qrr, Krr, Vtt, AO);

  gemm_bt<float><<<dim3(20, 32), 256, 0, stream>>>(AO, WoT, out, 4096, 2560, 4096);
}

// Round 4
// 439.184 us; speedup vs baseline: 1.6332x; 1.1811x over previous
//
#include <hip/hip_runtime.h>

typedef unsigned short u16;
typedef unsigned int u32;
using bf16x8 = __attribute__((ext_vector_type(8))) __bf16;
using f32x4  = __attribute__((ext_vector_type(4))) float;

typedef const void __attribute__((address_space(1)))* gas1p;
typedef void __attribute__((address_space(3)))* las3p;

__device__ __forceinline__ void gload16(const void* g, void* l) {
  __builtin_amdgcn_global_load_lds((gas1p)g, (las3p)l, 16, 0, 0);
}

__device__ __forceinline__ u16 f2bf(float f) {
  union { float f; unsigned u; } v; v.f = f;
  unsigned r = v.u + 0x7FFFu + ((v.u >> 16) & 1u);
  return (u16)(r >> 16);
}
__device__ __forceinline__ float bf2f(u16 h) {
  union { unsigned u; float f; } v; v.u = ((unsigned)h) << 16;
  return v.f;
}

// ---------------- x fp32 -> bf16 ----------------
__global__ __launch_bounds__(256)
void cvt_f32_bf16(const float4* __restrict__ in, uint2* __restrict__ out, int n4) {
  int i = blockIdx.x * 256 + threadIdx.x;
  if (i >= n4) return;
  float4 v = in[i];
  uint2 o;
  o.x = (unsigned)f2bf(v.x) | ((unsigned)f2bf(v.y) << 16);
  o.y = (unsigned)f2bf(v.z) | ((unsigned)f2bf(v.w) << 16);
  out[i] = o;
}

// ---------------- W (R x C fp32) -> out (C x R bf16) ----------------
__global__ __launch_bounds__(256)
void transpose_w(const float* __restrict__ in, u16* __restrict__ out, int R, int C) {
  __shared__ float tile[32][33];
  const int tx = threadIdx.x & 31, ty = threadIdx.x >> 5;
  const int r0 = blockIdx.y * 32, c0 = blockIdx.x * 32;
#pragma unroll
  for (int i = 0; i < 4; i++)
    tile[ty + i * 8][tx] = in[(size_t)(r0 + ty + i * 8) * C + c0 + tx];
  __syncthreads();
#pragma unroll
  for (int i = 0; i < 4; i++)
    out[(size_t)(c0 + ty + i * 8) * R + r0 + tx] = f2bf(tile[tx][ty + i * 8]);
}

// ---------------- V slice of QKV -> Vt (b,kv,d,l) bf16 ----------------
__global__ __launch_bounds__(256)
void transpose_v(const u16* __restrict__ QKV, u16* __restrict__ Vt) {
  __shared__ u16 tile[32][34];
  const int tx = threadIdx.x & 31, ty = threadIdx.x >> 5;
  const int l0 = blockIdx.x * 32, d0 = blockIdx.y * 32;
  const int bkv = blockIdx.z;
  const int b = bkv >> 3, kvh = bkv & 7;
#pragma unroll
  for (int i = 0; i < 4; i++)
    tile[ty + i * 8][tx] =
        QKV[(size_t)(b * 2048 + l0 + ty + i * 8) * 6144 + 5120 + kvh * 128 + d0 + tx];
  __syncthreads();
#pragma unroll
  for (int i = 0; i < 4; i++)
    Vt[((size_t)bkv * 128 + d0 + ty + i * 8) * 2048 + l0 + tx] = tile[tx][ty + i * 8];
}

// ---------------- RMSNorm + RoPE (+1/sqrt(128) folded into Q) ----------------
__global__ __launch_bounds__(256)
void norm_rope(const u16* __restrict__ QKV, const float* __restrict__ qw,
               const float* __restrict__ kw, const float* __restrict__ cosp,
               const float* __restrict__ sinp, u16* __restrict__ Qr,
               u16* __restrict__ Kr) {
  const int rid = blockIdx.x * 4 + (threadIdx.x >> 6);
  const int lane = threadIdx.x & 63;
  const int head = rid % 40;
  const int bl = rid / 40;               // b*2048 + l
  const int b = bl >> 11, l = bl & 2047;
  const u16* src; const float* w; u16* dst; float scale;
  if (head < 32) {
    src = QKV + (size_t)bl * 6144 + head * 128;
    w = qw;
    dst = Qr + ((size_t)(b * 32 + head) * 2048 + l) * 128;
    scale = 0.08838834764831845f;        // 1/sqrt(128)
  } else {
    const int kvh = head - 32;
    src = QKV + (size_t)bl * 6144 + 4096 + kvh * 128;
    w = kw;
    dst = Kr + ((size_t)(b * 8 + kvh) * 2048 + l) * 128;
    scale = 1.0f;
  }
  float lo = bf2f(src[lane]);
  float hi = bf2f(src[lane + 64]);
  float ss = lo * lo + hi * hi;
#pragma unroll
  for (int m = 1; m < 64; m <<= 1) ss += __shfl_xor(ss, m, 64);
  const float rstd = rsqrtf(ss * (1.0f / 128.0f) + 1e-6f) * scale;
  const float nlo = lo * rstd * w[lane];
  const float nhi = hi * rstd * w[lane + 64];
  const float* cb = cosp + (size_t)bl * 128;
  const float* sb = sinp + (size_t)bl * 128;
  dst[lane]      = f2bf(nlo * cb[lane]      - nhi * sb[lane]);
  dst[lane + 64] = f2bf(nhi * cb[lane + 64] + nlo * sb[lane + 64]);
}

// ======= 256x256 8-phase GEMM (m201-style): C(MxN) = A(MxK) * Bt(NxK)^T =====
// 512 thr = 8 waves (2M x 4N); per-wave 128x64 out; BK=64; LDS 128 KiB dyn.
// XOR swizzle: 16B-chunk ^= (row&7), staged via pre-swizzled global source.
#define ABUF(b) ((char*)smem + (b) * 32768)
#define BBUF(b) ((char*)smem + 65536 + (b) * 32768)
#define STG_A(h, b, kk)                                                     \
  { gload16(Ab + (size_t)aG[h][0] + (kk), ABUF(b) + aL[h][0]);              \
    gload16(Ab + (size_t)aG[h][1] + (kk), ABUF(b) + aL[h][1]); }
#define STG_B(h, b, kk)                                                     \
  { gload16(Bb + (size_t)bG[h][0] + (kk), BBUF(b) + bL[h][0]);              \
    gload16(Bb + (size_t)bG[h][1] + (kk), BBUF(b) + bL[h][1]); }
#define LDA(mh, b)                                                          \
  { _Pragma("unroll") for (int i = 0; i < 4; i++)                           \
    _Pragma("unroll") for (int ks = 0; ks < 2; ks++) {                      \
      const int row = wm * 128 + ((mh) * 4 + i) * 16 + fr;                  \
      af[i][ks] = *(const bf16x8*)(ABUF(b) + row * 128 +                    \
                                   ((((ks << 2) + fq) ^ (row & 7)) << 4));  \
    } }
#define LDB(nh, b)                                                          \
  { _Pragma("unroll") for (int j = 0; j < 2; j++)                           \
    _Pragma("unroll") for (int ks = 0; ks < 2; ks++) {                      \
      const int row = wn * 64 + ((nh) * 2 + j) * 16 + fr;                   \
      bb[nh][j][ks] = *(const bf16x8*)(BBUF(b) + row * 128 +                \
                                   ((((ks << 2) + fq) ^ (row & 7)) << 4));  \
    } }
#define MMA(mh, nh)                                                         \
  { __builtin_amdgcn_s_setprio(1);                                          \
    _Pragma("unroll") for (int i = 0; i < 4; i++)                           \
    _Pragma("unroll") for (int j = 0; j < 2; j++) {                         \
      acc[(mh) * 4 + i][(nh) * 2 + j] = __builtin_amdgcn_mfma_f32_16x16x32_bf16( \
          af[i][0], bb[nh][j][0], acc[(mh) * 4 + i][(nh) * 2 + j], 0, 0, 0);\
      acc[(mh) * 4 + i][(nh) * 2 + j] = __builtin_amdgcn_mfma_f32_16x16x32_bf16( \
          af[i][1], bb[nh][j][1], acc[(mh) * 4 + i][(nh) * 2 + j], 0, 0, 0);\
    }                                                                       \
    __builtin_amdgcn_s_setprio(0); }
#define BAR __builtin_amdgcn_s_barrier()
#define WLG { asm volatile("s_waitcnt lgkmcnt(0)" ::: "memory");            \
              __builtin_amdgcn_sched_barrier(0); }
#define WVM2 asm volatile("s_waitcnt vmcnt(2)" ::: "memory")
#define WVM4 asm volatile("s_waitcnt vmcnt(4)" ::: "memory")

template <typename CT>
__global__ __launch_bounds__(512, 2)
void gemm8(const u16* __restrict__ A, const u16* __restrict__ Bt,
           CT* __restrict__ C, int M, int N, int K, int MB) {
  extern __shared__ u16 smem[];
  const int tid = threadIdx.x, lane = tid & 63, wid = tid >> 6;
  const int wm = wid >> 2, wn = wid & 3;
  const int fr = lane & 15, fq = lane >> 4;
  // bijective XCD remap (gridDim.x % 8 == 0), column-major chunks
  const int q = (int)gridDim.x >> 3;
  const int wg = ((int)blockIdx.x & 7) * q + ((int)blockIdx.x >> 3);
  const int bx = wg / MB, by = wg - bx * MB;
  const int m0 = by * 256, n0 = bx * 256;

  // staging maps: half h of A = rows {bit6==h}; of B = rows {bit5==h}
  int aL[2][2], bL[2][2], aG[2][2], bG[2][2];
#pragma unroll
  for (int l = 0; l < 2; l++) {
    const int c = tid + (l << 9);
    const int lrow = c >> 3, ch = c & 7;
#pragma unroll
    for (int h = 0; h < 2; h++) {
      const int sa = (lrow & 63) + (l << 7) + h * 64;
      aL[h][l] = sa * 128 + ch * 16;
      aG[h][l] = sa * K + ((ch ^ (sa & 7)) << 3);
      const int sb = (lrow & 31) + ((lrow >> 5) << 6) + h * 32;
      bL[h][l] = sb * 128 + ch * 16;
      bG[h][l] = sb * K + ((ch ^ (sb & 7)) << 3);
    }
  }
  const u16* Ab = A + (size_t)m0 * K;
  const u16* Bb = Bt + (size_t)n0 * K;

  f32x4 acc[8][4];
#pragma unroll
  for (int i = 0; i < 8; i++)
#pragma unroll
    for (int j = 0; j < 4; j++)
#pragma unroll
      for (int r = 0; r < 4; r++) acc[i][j][r] = 0.f;

  bf16x8 af[4][2], bb[2][2][2];

  const int NT = K >> 6, NI = NT >> 1;
  // prologue: stage tile 0 -> buf0
  STG_A(0, 0, 0); STG_B(0, 0, 0); STG_B(1, 0, 0); STG_A(1, 0, 0);
  asm volatile("s_waitcnt vmcnt(0)" ::: "memory");
  BAR;

  for (int it = 0; it < NI; ++it) {
    const int kk1 = (2 * it + 1) << 6;
    int t2 = 2 * it + 2; if (t2 >= NT) t2 = 0;
    const int kk2 = t2 << 6;
    // p1
    LDA(0, 0); LDB(0, 0); STG_A(0, 1, kk1);
    BAR; WLG; MMA(0, 0); BAR;
    // p2
    LDB(1, 0); STG_B(0, 1, kk1); WVM4;
    BAR; WLG; MMA(0, 1); BAR;
    // p3
    LDA(1, 0); STG_B(1, 1, kk1);
    BAR; WLG; MMA(1, 1); BAR;
    // p4
    STG_A(1, 1, kk1); WVM2;
    BAR; MMA(1, 0); BAR;
    // p5
    LDA(0, 1); LDB(0, 1); STG_A(0, 0, kk2);
    BAR; WLG; MMA(0, 0); BAR;
    // p6
    LDB(1, 1); STG_B(0, 0, kk2); WVM4;
    BAR; WLG; MMA(0, 1); BAR;
    // p7
    LDA(1, 1); STG_B(1, 0, kk2);
    BAR; WLG; MMA(1, 1); BAR;
    // p8
    STG_A(1, 0, kk2); WVM2;
    BAR; MMA(1, 0); BAR;
  }
  asm volatile("s_waitcnt vmcnt(0)" ::: "memory");

  // epilogue: per-wave 128x64 tile
#pragma unroll
  for (int i = 0; i < 8; i++) {
    const int row0 = m0 + wm * 128 + i * 16 + fq * 4;
#pragma unroll
    for (int j = 0; j < 4; j++) {
      const int col = n0 + wn * 64 + j * 16 + fr;
#pragma unroll
      for (int r = 0; r < 4; r++) {
        const size_t idx = (size_t)(row0 + r) * N + col;
        if constexpr (sizeof(CT) == 2) C[idx] = f2bf(acc[i][j][r]);
        else C[idx] = acc[i][j][r];
      }
    }
  }
}

// ---------------- Flash attention, causal GQA (unchanged from R3) ----------
__global__ __launch_bounds__(256, 2)
void attn_fwd(const u16* __restrict__ Qr, const u16* __restrict__ Kr,
              const u16* __restrict__ Vt, u16* __restrict__ AO) {
  const int L = 2048, DH = 128;
  __shared__ u16 Ks[2][64 * 128];   // [buf][key][d], XOR-swizzled
  __shared__ u16 Vs[2][128 * 64];   // [buf][d][key], XOR-swizzled
  const int tid = threadIdx.x, lane = tid & 63, wid = tid >> 6;
  const int fr = lane & 15, fq = lane >> 4;
  const int j = blockIdx.x >> 4;           // q-tile pair index [0,32)
  const int grp = blockIdx.x & 15;
  const int kvh = grp >> 1, b = grp & 1;
  const int h = kvh * 4 + wid;

  const u16* Kbase = Kr + (size_t)(b * 8 + kvh) * L * DH;
  const u16* Vbase = Vt + (size_t)(b * 8 + kvh) * DH * L;

  int Dly[4], kOff[4], vOff[4];
#pragma unroll
  for (int p = 0; p < 4; p++) {
    const int D = (tid + p * 256) * 16;
    Dly[p] = D;
    const int kr = D >> 8, kc = ((D >> 4) & 15) ^ (kr & 7);
    kOff[p] = kr * 128 + kc * 8;
    const int vr = D >> 7, vc = ((D >> 4) & 7) ^ (vr & 7);
    vOff[p] = vr * 2048 + vc * 8;
  }

  const bool B5 = (lane & 32) != 0;
  const bool A4 = (lane & 16) != 0;

  auto stage = [&](int kt, int bufi) {
    const int k0 = kt * 64;
#pragma unroll
    for (int p = 0; p < 4; p++) {
      gload16(Kbase + (size_t)k0 * 128 + kOff[p], (char*)&Ks[bufi][0] + Dly[p]);
      gload16(Vbase + k0 + vOff[p], (char*)&Vs[bufi][0] + Dly[p]);
    }
  };

  for (int half = 0; half < 2; half++) {
    const int t = half ? 63 - j : j;
    const int nk = (t >> 1) + 1;

    bf16x8 qf[2][4];
#pragma unroll
    for (int g = 0; g < 2; g++) {
      const int qq = t * 32 + g * 16 + fr;
      const u16* qbase = Qr + ((size_t)(b * 32 + h) * L + qq) * DH + fq * 8;
#pragma unroll
      for (int dt = 0; dt < 4; dt++) qf[g][dt] = *(const bf16x8*)(qbase + dt * 32);
    }
    asm volatile("s_waitcnt vmcnt(0)" ::: "memory");

    f32x4 o[2][8];
#pragma unroll
    for (int g = 0; g < 2; g++)
#pragma unroll
      for (int d = 0; d < 8; d++)
#pragma unroll
        for (int r = 0; r < 4; r++) o[g][d][r] = 0.f;
    float mrow[2] = {-__builtin_huge_valf(), -__builtin_huge_valf()};
    float lrow[2] = {0.f, 0.f};

    __builtin_amdgcn_s_barrier();
    stage(0, 0);
    int cur = 0;

    for (int kt = 0; kt < nk; kt++) {
      if (kt + 1 < nk) {
        stage(kt + 1, cur ^ 1);
        asm volatile("s_waitcnt vmcnt(8)" ::: "memory");
      } else {
        asm volatile("s_waitcnt vmcnt(0)" ::: "memory");
      }
      __builtin_amdgcn_s_barrier();

      const u16* KsB = &Ks[cur][0];
      const u16* VsB = &Vs[cur][0];
      const int k0 = kt * 64;

      f32x4 s4[2][4];
#pragma unroll
      for (int g = 0; g < 2; g++)
#pragma unroll
        for (int ni = 0; ni < 4; ni++)
#pragma unroll
          for (int r = 0; r < 4; r++) s4[g][ni][r] = 0.f;
#pragma unroll
      for (int ni = 0; ni < 4; ni++) {
        const int krow = ni * 16 + fr;
        const int sw = (krow & 7) << 4;
#pragma unroll
        for (int dt = 0; dt < 4; dt++) {
          const int off = (krow * 256 + dt * 64 + fq * 16) ^ sw;
          bf16x8 kf = *(const bf16x8*)((const char*)KsB + off);
          s4[0][ni] = __builtin_amdgcn_mfma_f32_16x16x32_bf16(kf, qf[0][dt], s4[0][ni], 0, 0, 0);
          s4[1][ni] = __builtin_amdgcn_mfma_f32_16x16x32_bf16(kf, qf[1][dt], s4[1][ni], 0, 0, 0);
        }
      }

      if (kt == nk - 1) {
#pragma unroll
        for (int g = 0; g < 2; g++) {
          const int qq = t * 32 + g * 16 + fr;
#pragma unroll
          for (int ni = 0; ni < 4; ni++)
#pragma unroll
            for (int r = 0; r < 4; r++)
              if (k0 + ni * 16 + fq * 4 + r > qq) s4[g][ni][r] = -1e30f;
        }
      }

      bf16x8 pb[2][2];
#pragma unroll
      for (int g = 0; g < 2; g++) {
        float mt = s4[g][0][0];
#pragma unroll
        for (int ni = 0; ni < 4; ni++)
#pragma unroll
          for (int r = 0; r < 4; r++) mt = fmaxf(mt, s4[g][ni][r]);
        mt = fmaxf(mt, __shfl_xor(mt, 16, 64));
        mt = fmaxf(mt, __shfl_xor(mt, 32, 64));

        if (!__all(mt <= mrow[g] + 8.f)) {
          const float mn = fmaxf(mrow[g], mt);
          const float corr = exp2f((mrow[g] - mn) * 1.44269504f);
          mrow[g] = mn;
          lrow[g] *= corr;
#pragma unroll
          for (int d = 0; d < 8; d++)
#pragma unroll
            for (int r = 0; r < 4; r++) o[g][d][r] *= corr;
        }

        const float ml = mrow[g] * 1.44269504f;
        float rs = 0.f;
#pragma unroll
        for (int ni = 0; ni < 4; ni++)
#pragma unroll
          for (int r = 0; r < 4; r++) {
            const float pv = exp2f(fmaf(s4[g][ni][r], 1.44269504f, -ml));
            s4[g][ni][r] = pv;
            rs += pv;
          }
        rs += __shfl_xor(rs, 16, 64);
        rs += __shfl_xor(rs, 32, 64);
        lrow[g] += rs;

        u32 pk[4][2];
#pragma unroll
        for (int ni = 0; ni < 4; ni++) {
          pk[ni][0] = __builtin_amdgcn_perm(__float_as_uint(s4[g][ni][1]),
                                            __float_as_uint(s4[g][ni][0]), 0x07060302u);
          pk[ni][1] = __builtin_amdgcn_perm(__float_as_uint(s4[g][ni][3]),
                                            __float_as_uint(s4[g][ni][2]), 0x07060302u);
        }
#pragma unroll
        for (int ks = 0; ks < 2; ks++) {
          u32 r00 = pk[2 * ks + 0][0], r01 = pk[2 * ks + 0][1];
          u32 r10 = pk[2 * ks + 1][0], r11 = pk[2 * ks + 1][1];
          u32 e0 = __shfl_xor(B5 ? r00 : r10, 32, 64);
          u32 t00 = B5 ? e0 : r00, t10 = B5 ? r10 : e0;
          u32 e1 = __shfl_xor(B5 ? r01 : r11, 32, 64);
          u32 t01 = B5 ? e1 : r01, t11 = B5 ? r11 : e1;
          u32 e2 = __shfl_xor(A4 ? t00 : t10, 16, 64);
          u32 u00 = A4 ? e2 : t00, u10 = A4 ? t10 : e2;
          u32 e3 = __shfl_xor(A4 ? t01 : t11, 16, 64);
          u32 u01 = A4 ? e3 : t01, u11 = A4 ? t11 : e3;
          union { u32 u[4]; bf16x8 v; } pbv;
          pbv.u[0] = u00; pbv.u[1] = u01; pbv.u[2] = u10; pbv.u[3] = u11;
          pb[g][ks] = pbv.v;
        }
      }

#pragma unroll
      for (int d = 0; d < 8; d++) {
        const int vrow = d * 16 + fr;
        const int sw = (vrow & 7) << 4;
#pragma unroll
        for (int ks = 0; ks < 2; ks++) {
          const int off = (vrow * 128 + ks * 64 + fq * 16) ^ sw;
          bf16x8 vf = *(const bf16x8*)((const char*)VsB + off);
          o[0][d] = __builtin_amdgcn_mfma_f32_16x16x32_bf16(vf, pb[0][ks], o[0][d], 0, 0, 0);
          o[1][d] = __builtin_amdgcn_mfma_f32_16x16x32_bf16(vf, pb[1][ks], o[1][d], 0, 0, 0);
        }
      }
      __builtin_amdgcn_s_barrier();
      cur ^= 1;
    }

#pragma unroll
    for (int g = 0; g < 2; g++) {
      const float inv = 1.f / lrow[g];
      const int qq = t * 32 + g * 16 + fr;
      u16* obase = AO + ((size_t)b * L + qq) * 4096 + h * 128 + fq * 4;
#pragma unroll
      for (int d = 0; d < 8; d++) {
        uint2 w;
        w.x = (u32)f2bf(o[g][d][0] * inv) | ((u32)f2bf(o[g][d][1] * inv) << 16);
        w.y = (u32)f2bf(o[g][d][2] * inv) | ((u32)f2bf(o[g][d][3] * inv) << 16);
        *(uint2*)(obase + d * 16) = w;
      }
    }
  }
}

// ---------------- launcher ----------------
extern "C" void kernel_launch(void* const* d_in, const int* in_sizes, int n_in,
                              void* d_out, int out_size, void* d_ws, size_t ws_size,
                              hipStream_t stream) {
  const float* x    = (const float*)d_in[0];
  const float* Wq   = (const float*)d_in[1];
  const float* Wk   = (const float*)d_in[2];
  const float* Wv   = (const float*)d_in[3];
  const float* Wo   = (const float*)d_in[4];
  const float* qw   = (const float*)d_in[5];
  const float* kw   = (const float*)d_in[6];
  const float* cosp = (const float*)d_in[7];
  const float* sinp = (const float*)d_in[8];
  float* out = (float*)d_out;
  char* ws = (char*)d_ws;

  u16* xb    = (u16*)(ws);                 // 4096x2560 bf16
  u16* WqkvT = (u16*)(ws + 20971520);      // 6144x2560 bf16
  u16* WoT   = (u16*)(ws + 52428800);      // 2560x4096 bf16
  u16* QKV   = (u16*)(ws + 73400320);      // 4096x6144 bf16
  u16* AO    = QKV;                        // alias: QKV dead before attn writes
  u16* Qrr   = (u16*)(ws + 123731968);
  u16* Krr   = (u16*)(ws + 157286400);
  u16* Vtt   = (u16*)(ws + 165675008);

  hipFuncSetAttribute(reinterpret_cast<const void*>(&gemm8<u16>),
                      hipFuncAttributeMaxDynamicSharedMemorySize, 131072);
  hipFuncSetAttribute(reinterpret_cast<const void*>(&gemm8<float>),
                      hipFuncAttributeMaxDynamicSharedMemorySize, 131072);

  cvt_f32_bf16<<<10240, 256, 0, stream>>>((const float4*)x, (uint2*)xb, 2621440);
  transpose_w<<<dim3(128, 80), 256, 0, stream>>>(Wq, WqkvT, 2560, 4096);
  transpose_w<<<dim3(32, 80), 256, 0, stream>>>(Wk, WqkvT + (size_t)4096 * 2560, 2560, 1024);
  transpose_w<<<dim3(32, 80), 256, 0, stream>>>(Wv, WqkvT + (size_t)5120 * 2560, 2560, 1024);
  transpose_w<<<dim3(80, 128), 256, 0, stream>>>(Wo, WoT, 4096, 2560);

  gemm8<u16><<<384, 512, 131072, stream>>>(xb, WqkvT, QKV, 4096, 6144, 2560, 16);

  norm_rope<<<40960, 256, 0, stream>>>(QKV, qw, kw, cosp, sinp, Qrr, Krr);
  transpose_v<<<dim3(64, 4, 16), 256, 0, stream>>>(QKV, Vtt);

  attn_fwd<<<dim3(512), 256, 0, stream>>>(Qrr, Krr, Vtt, AO);

  gemm8<float><<<160, 512, 131072, stream>>>(AO, WoT, out, 4096, 2560, 4096, 16);
}

// Round 6
// 423.599 us; speedup vs baseline: 1.6933x; 1.0368x over previous
//
#include <hip/hip_runtime.h>

typedef unsigned short u16;
typedef unsigned int u32;
using bf16x8 = __attribute__((ext_vector_type(8))) __bf16;
using f32x4  = __attribute__((ext_vector_type(4))) float;

typedef const void __attribute__((address_space(1)))* gas1p;
typedef void __attribute__((address_space(3)))* las3p;

__device__ __forceinline__ void gload16(const void* g, void* l) {
  __builtin_amdgcn_global_load_lds((gas1p)g, (las3p)l, 16, 0, 0);
}

__device__ __forceinline__ u16 f2bf(float f) {
  union { float f; unsigned u; } v; v.f = f;
  unsigned r = v.u + 0x7FFFu + ((v.u >> 16) & 1u);
  return (u16)(r >> 16);
}
__device__ __forceinline__ float bf2f(u16 h) {
  union { unsigned u; float f; } v; v.u = ((unsigned)h) << 16;
  return v.f;
}

// ---------------- x fp32 -> bf16 ----------------
__global__ __launch_bounds__(256)
void cvt_f32_bf16(const float4* __restrict__ in, uint2* __restrict__ out, int n4) {
  int i = blockIdx.x * 256 + threadIdx.x;
  if (i >= n4) return;
  float4 v = in[i];
  uint2 o;
  o.x = (unsigned)f2bf(v.x) | ((unsigned)f2bf(v.y) << 16);
  o.y = (unsigned)f2bf(v.z) | ((unsigned)f2bf(v.w) << 16);
  out[i] = o;
}

// ---------------- W (R x C fp32) -> out (C x R bf16) ----------------
__global__ __launch_bounds__(256)
void transpose_w(const float* __restrict__ in, u16* __restrict__ out, int R, int C) {
  __shared__ float tile[32][33];
  const int tx = threadIdx.x & 31, ty = threadIdx.x >> 5;
  const int r0 = blockIdx.y * 32, c0 = blockIdx.x * 32;
#pragma unroll
  for (int i = 0; i < 4; i++)
    tile[ty + i * 8][tx] = in[(size_t)(r0 + ty + i * 8) * C + c0 + tx];
  __syncthreads();
#pragma unroll
  for (int i = 0; i < 4; i++)
    out[(size_t)(c0 + ty + i * 8) * R + r0 + tx] = f2bf(tile[tx][ty + i * 8]);
}

// ---------------- V slice of QKV -> Vt (b,kv,d,l) bf16 ----------------
__global__ __launch_bounds__(256)
void transpose_v(const u16* __restrict__ QKV, u16* __restrict__ Vt) {
  __shared__ u16 tile[32][34];
  const int tx = threadIdx.x & 31, ty = threadIdx.x >> 5;
  const int l0 = blockIdx.x * 32, d0 = blockIdx.y * 32;
  const int bkv = blockIdx.z;
  const int b = bkv >> 3, kvh = bkv & 7;
#pragma unroll
  for (int i = 0; i < 4; i++)
    tile[ty + i * 8][tx] =
        QKV[(size_t)(b * 2048 + l0 + ty + i * 8) * 6144 + 5120 + kvh * 128 + d0 + tx];
  __syncthreads();
#pragma unroll
  for (int i = 0; i < 4; i++)
    Vt[((size_t)bkv * 128 + d0 + ty + i * 8) * 2048 + l0 + tx] = tile[tx][ty + i * 8];
}

// ---------------- RMSNorm + RoPE (+1/sqrt(128) folded into Q) ----------------
__global__ __launch_bounds__(256)
void norm_rope(const u16* __restrict__ QKV, const float* __restrict__ qw,
               const float* __restrict__ kw, const float* __restrict__ cosp,
               const float* __restrict__ sinp, u16* __restrict__ Qr,
               u16* __restrict__ Kr) {
  const int rid = blockIdx.x * 4 + (threadIdx.x >> 6);
  const int lane = threadIdx.x & 63;
  const int head = rid % 40;
  const int bl = rid / 40;               // b*2048 + l
  const int b = bl >> 11, l = bl & 2047;
  const u16* src; const float* w; u16* dst; float scale;
  if (head < 32) {
    src = QKV + (size_t)bl * 6144 + head * 128;
    w = qw;
    dst = Qr + ((size_t)(b * 32 + head) * 2048 + l) * 128;
    scale = 0.08838834764831845f;        // 1/sqrt(128)
  } else {
    const int kvh = head - 32;
    src = QKV + (size_t)bl * 6144 + 4096 + kvh * 128;
    w = kw;
    dst = Kr + ((size_t)(b * 8 + kvh) * 2048 + l) * 128;
    scale = 1.0f;
  }
  float lo = bf2f(src[lane]);
  float hi = bf2f(src[lane + 64]);
  float ss = lo * lo + hi * hi;
#pragma unroll
  for (int m = 1; m < 64; m <<= 1) ss += __shfl_xor(ss, m, 64);
  const float rstd = rsqrtf(ss * (1.0f / 128.0f) + 1e-6f) * scale;
  const float nlo = lo * rstd * w[lane];
  const float nhi = hi * rstd * w[lane + 64];
  const float* cb = cosp + (size_t)bl * 128;
  const float* sb = sinp + (size_t)bl * 128;
  dst[lane]      = f2bf(nlo * cb[lane]      - nhi * sb[lane]);
  dst[lane + 64] = f2bf(nhi * cb[lane + 64] + nlo * sb[lane + 64]);
}

// ====== 128 x (NJ*64) 3-phase GEMM: C(MxN) = A(MxK) * Bt(NxK)^T ======
// 512 thr = 8 waves (2M x 4N). Per-wave 64 rows x NJ col-frags (interleaved:
// wave wn owns cols j*64 + wn*16). BK=64. Invariant (fixes R5 race): every
// ds_read chunk was guaranteed by a WVMn + BARRIER pair in an EARLIER phase;
// each phase's WVMn retires exactly the chunks the NEXT phase reads.
// Per-wave FIFO (issue order A,A,B0..B{NJ-1}):
//  NJ=6: prologue W(4); phases W(5)/W(6)/W(4)   (outstanding never < 4)
//  NJ=5: prologue W(3); phases W(4)/W(5)/W(3)
#define SMEMA(c) (smem + (c) * 16384)
#define SMEMB(c) (smem + 32768 + (c) * (NJ * 8192))
#define STGA(c, kk)                                                         \
  { gload16(Ab + stgo + (kk), SMEMA(c) + (tid << 4));                       \
    gload16(Ab + stgo + (size_t)64 * K + (kk), SMEMA(c) + 8192 + (tid << 4)); }
#define STGB(c, kk, q)                                                      \
  gload16(Bb + stgo + (size_t)(q) * 64 * K + (kk),                          \
          SMEMB(c) + ((q) << 13) + (tid << 4))
#define LDA(c)                                                              \
  { _Pragma("unroll") for (int i = 0; i < 4; i++)                           \
    _Pragma("unroll") for (int ks = 0; ks < 2; ks++) {                      \
      const int row = wm * 64 + i * 16 + fr;                                \
      af[i][ks] = *(const bf16x8*)(SMEMA(c) + row * 128 +                   \
                                   ((((ks << 2) + fq) ^ (row & 7)) << 4)); } }
#define LDB(c, j, d)                                                        \
  { _Pragma("unroll") for (int ks = 0; ks < 2; ks++) {                      \
      const int row = (j) * 64 + wn * 16 + fr;                              \
      d[ks] = *(const bf16x8*)(SMEMB(c) + row * 128 +                       \
                               ((((ks << 2) + fq) ^ (row & 7)) << 4)); } }
#define MMAJ(j, bv)                                                         \
  _Pragma("unroll") for (int i = 0; i < 4; i++) {                           \
    acc[i][j] = __builtin_amdgcn_mfma_f32_16x16x32_bf16(af[i][0], bv[0],    \
                                                        acc[i][j], 0, 0, 0);\
    acc[i][j] = __builtin_amdgcn_mfma_f32_16x16x32_bf16(af[i][1], bv[1],    \
                                                        acc[i][j], 0, 0, 0); }
#define BAR __builtin_amdgcn_s_barrier()
#define WLG { asm volatile("s_waitcnt lgkmcnt(0)" ::: "memory");            \
              __builtin_amdgcn_sched_barrier(0); }
#define WVMn(n) asm volatile("s_waitcnt vmcnt(" #n ")" ::: "memory")
#define SP1 __builtin_amdgcn_s_setprio(1)
#define SP0 __builtin_amdgcn_s_setprio(0)

template <int NJ, typename CT>
__global__ __launch_bounds__(512, 2)
void gemmN(const u16* __restrict__ A, const u16* __restrict__ Bt,
           CT* __restrict__ C, int N, int K, int MT) {
  extern __shared__ char smem[];
  const int tid = threadIdx.x, lane = tid & 63, wid = tid >> 6;
  const int wm = wid >> 2, wn = wid & 3;
  const int fr = lane & 15, fq = lane >> 4;
  // bijective XCD remap (gridDim.x % 8 == 0); consecutive wgs share B-panel
  const int qx = (int)gridDim.x >> 3;
  const int wg = ((int)blockIdx.x & 7) * qx + ((int)blockIdx.x >> 3);
  const int bx = wg / MT, by = wg - bx * MT;
  const int m0 = by * 128, n0 = bx * (NJ * 64);
  const u16* Ab = A + (size_t)m0 * K;
  const u16* Bb = Bt + (size_t)n0 * K;
  // staging source offset (inverse-swizzled): thread covers row=tid>>3, chunk=tid&7
  const size_t stgo =
      (size_t)(tid >> 3) * K + (size_t)(((tid & 7) ^ ((tid >> 3) & 7)) << 3);

  f32x4 acc[4][NJ];
#pragma unroll
  for (int i = 0; i < 4; i++)
#pragma unroll
    for (int j = 0; j < NJ; j++)
#pragma unroll
      for (int r = 0; r < 4; r++) acc[i][j][r] = 0.f;

  bf16x8 af[4][2], b0[2], b1[2];
  const int NT = K >> 6;

  // prologue: stage tile 0 -> buf 0; retire A,B0,B1 then BARRIER
  STGA(0, 0);
#pragma unroll
  for (int q2 = 0; q2 < NJ; q2++) STGB(0, 0, q2);
  if constexpr (NJ == 6) { WVMn(4); } else { WVMn(3); }
  BAR;

  for (int t = 0; t < NT; t++) {
    const int c = t & 1, cn = c ^ 1;
    const int kn = ((t + 1 == NT) ? 0 : (t + 1)) << 6;
    // ---- P1: read A,B0,B1 (guaranteed); stage A',B0'; wait -> B2,B3 done
    LDA(c); LDB(c, 0, b0); LDB(c, 1, b1);
    STGA(cn, kn); STGB(cn, kn, 0);
    if constexpr (NJ == 6) { WVMn(5); } else { WVMn(4); }
    BAR; WLG; SP1; MMAJ(0, b0); MMAJ(1, b1); SP0; BAR;
    // ---- P2: read B2,B3; stage B1'..; wait -> B4(,B5) done
    LDB(c, 2, b0); LDB(c, 3, b1);
    STGB(cn, kn, 1); STGB(cn, kn, 2);
    if constexpr (NJ == 6) { STGB(cn, kn, 3); WVMn(6); } else { WVMn(5); }
    BAR; WLG; SP1; MMAJ(2, b0); MMAJ(3, b1); SP0; BAR;
    // ---- P3: read B4(,B5); stage rest; wait -> A',B0',B1' done
    LDB(c, 4, b0);
    if constexpr (NJ == 6) {
      LDB(c, 5, b1);
      STGB(cn, kn, 4); STGB(cn, kn, 5); WVMn(4);
    } else {
      STGB(cn, kn, 3); STGB(cn, kn, 4); WVMn(3);
    }
    BAR; WLG; SP1; MMAJ(4, b0);
    if constexpr (NJ == 6) MMAJ(5, b1);
    SP0; BAR;
  }
  WVMn(0);

  // epilogue
#pragma unroll
  for (int i = 0; i < 4; i++) {
    const int row0 = m0 + wm * 64 + i * 16 + fq * 4;
#pragma unroll
    for (int j = 0; j < NJ; j++) {
      const int col = n0 + j * 64 + wn * 16 + fr;
#pragma unroll
      for (int r = 0; r < 4; r++) {
        const size_t idx = (size_t)(row0 + r) * N + col;
        if constexpr (sizeof(CT) == 2) C[idx] = f2bf(acc[i][j][r]);
        else C[idx] = acc[i][j][r];
      }
    }
  }
}

// ---------------- Flash attention, causal GQA (unchanged from R3) ----------
__global__ __launch_bounds__(256, 2)
void attn_fwd(const u16* __restrict__ Qr, const u16* __restrict__ Kr,
              const u16* __restrict__ Vt, u16* __restrict__ AO) {
  const int L = 2048, DH = 128;
  __shared__ u16 Ks[2][64 * 128];   // [buf][key][d], XOR-swizzled
  __shared__ u16 Vs[2][128 * 64];   // [buf][d][key], XOR-swizzled
  const int tid = threadIdx.x, lane = tid & 63, wid = tid >> 6;
  const int fr = lane & 15, fq = lane >> 4;
  const int j = blockIdx.x >> 4;           // q-tile pair index [0,32)
  const int grp = blockIdx.x & 15;
  const int kvh = grp >> 1, b = grp & 1;
  const int h = kvh * 4 + wid;

  const u16* Kbase = Kr + (size_t)(b * 8 + kvh) * L * DH;
  const u16* Vbase = Vt + (size_t)(b * 8 + kvh) * DH * L;

  int Dly[4], kOff[4], vOff[4];
#pragma unroll
  for (int p = 0; p < 4; p++) {
    const int D = (tid + p * 256) * 16;
    Dly[p] = D;
    const int kr = D >> 8, kc = ((D >> 4) & 15) ^ (kr & 7);
    kOff[p] = kr * 128 + kc * 8;
    const int vr = D >> 7, vc = ((D >> 4) & 7) ^ (vr & 7);
    vOff[p] = vr * 2048 + vc * 8;
  }

  const bool B5 = (lane & 32) != 0;
  const bool A4 = (lane & 16) != 0;

  auto stage = [&](int kt, int bufi) {
    const int k0 = kt * 64;
#pragma unroll
    for (int p = 0; p < 4; p++) {
      gload16(Kbase + (size_t)k0 * 128 + kOff[p], (char*)&Ks[bufi][0] + Dly[p]);
      gload16(Vbase + k0 + vOff[p], (char*)&Vs[bufi][0] + Dly[p]);
    }
  };

  for (int half = 0; half < 2; half++) {
    const int t = half ? 63 - j : j;
    const int nk = (t >> 1) + 1;

    bf16x8 qf[2][4];
#pragma unroll
    for (int g = 0; g < 2; g++) {
      const int qq = t * 32 + g * 16 + fr;
      const u16* qbase = Qr + ((size_t)(b * 32 + h) * L + qq) * DH + fq * 8;
#pragma unroll
      for (int dt = 0; dt < 4; dt++) qf[g][dt] = *(const bf16x8*)(qbase + dt * 32);
    }
    asm volatile("s_waitcnt vmcnt(0)" ::: "memory");

    f32x4 o[2][8];
#pragma unroll
    for (int g = 0; g < 2; g++)
#pragma unroll
      for (int d = 0; d < 8; d++)
#pragma unroll
        for (int r = 0; r < 4; r++) o[g][d][r] = 0.f;
    float mrow[2] = {-__builtin_huge_valf(), -__builtin_huge_valf()};
    float lrow[2] = {0.f, 0.f};

    __builtin_amdgcn_s_barrier();
    stage(0, 0);
    int cur = 0;

    for (int kt = 0; kt < nk; kt++) {
      if (kt + 1 < nk) {
        stage(kt + 1, cur ^ 1);
        asm volatile("s_waitcnt vmcnt(8)" ::: "memory");
      } else {
        asm volatile("s_waitcnt vmcnt(0)" ::: "memory");
      }
      __builtin_amdgcn_s_barrier();

      const u16* KsB = &Ks[cur][0];
      const u16* VsB = &Vs[cur][0];
      const int k0 = kt * 64;

      f32x4 s4[2][4];
#pragma unroll
      for (int g = 0; g < 2; g++)
#pragma unroll
        for (int ni = 0; ni < 4; ni++)
#pragma unroll
          for (int r = 0; r < 4; r++) s4[g][ni][r] = 0.f;
#pragma unroll
      for (int ni = 0; ni < 4; ni++) {
        const int krow = ni * 16 + fr;
        const int sw = (krow & 7) << 4;
#pragma unroll
        for (int dt = 0; dt < 4; dt++) {
          const int off = (krow * 256 + dt * 64 + fq * 16) ^ sw;
          bf16x8 kf = *(const bf16x8*)((const char*)KsB + off);
          s4[0][ni] = __builtin_amdgcn_mfma_f32_16x16x32_bf16(kf, qf[0][dt], s4[0][ni], 0, 0, 0);
          s4[1][ni] = __builtin_amdgcn_mfma_f32_16x16x32_bf16(kf, qf[1][dt], s4[1][ni], 0, 0, 0);
        }
      }

      if (kt == nk - 1) {
#pragma unroll
        for (int g = 0; g < 2; g++) {
          const int qq = t * 32 + g * 16 + fr;
#pragma unroll
          for (int ni = 0; ni < 4; ni++)
#pragma unroll
            for (int r = 0; r < 4; r++)
              if (k0 + ni * 16 + fq * 4 + r > qq) s4[g][ni][r] = -1e30f;
        }
      }

      bf16x8 pb[2][2];
#pragma unroll
      for (int g = 0; g < 2; g++) {
        float mt = s4[g][0][0];
#pragma unroll
        for (int ni = 0; ni < 4; ni++)
#pragma unroll
          for (int r = 0; r < 4; r++) mt = fmaxf(mt, s4[g][ni][r]);
        mt = fmaxf(mt, __shfl_xor(mt, 16, 64));
        mt = fmaxf(mt, __shfl_xor(mt, 32, 64));

        if (!__all(mt <= mrow[g] + 8.f)) {
          const float mn = fmaxf(mrow[g], mt);
          const float corr = exp2f((mrow[g] - mn) * 1.44269504f);
          mrow[g] = mn;
          lrow[g] *= corr;
#pragma unroll
          for (int d = 0; d < 8; d++)
#pragma unroll
            for (int r = 0; r < 4; r++) o[g][d][r] *= corr;
        }

        const float ml = mrow[g] * 1.44269504f;
        float rs = 0.f;
#pragma unroll
        for (int ni = 0; ni < 4; ni++)
#pragma unroll
          for (int r = 0; r < 4; r++) {
            const float pv = exp2f(fmaf(s4[g][ni][r], 1.44269504f, -ml));
            s4[g][ni][r] = pv;
            rs += pv;
          }
        rs += __shfl_xor(rs, 16, 64);
        rs += __shfl_xor(rs, 32, 64);
        lrow[g] += rs;

        u32 pk[4][2];
#pragma unroll
        for (int ni = 0; ni < 4; ni++) {
          pk[ni][0] = __builtin_amdgcn_perm(__float_as_uint(s4[g][ni][1]),
                                            __float_as_uint(s4[g][ni][0]), 0x07060302u);
          pk[ni][1] = __builtin_amdgcn_perm(__float_as_uint(s4[g][ni][3]),
                                            __float_as_uint(s4[g][ni][2]), 0x07060302u);
        }
#pragma unroll
        for (int ks = 0; ks < 2; ks++) {
          u32 r00 = pk[2 * ks + 0][0], r01 = pk[2 * ks + 0][1];
          u32 r10 = pk[2 * ks + 1][0], r11 = pk[2 * ks + 1][1];
          u32 e0 = __shfl_xor(B5 ? r00 : r10, 32, 64);
          u32 t00 = B5 ? e0 : r00, t10 = B5 ? r10 : e0;
          u32 e1 = __shfl_xor(B5 ? r01 : r11, 32, 64);
          u32 t01 = B5 ? e1 : r01, t11 = B5 ? r11 : e1;
          u32 e2 = __shfl_xor(A4 ? t00 : t10, 16, 64);
          u32 u00 = A4 ? e2 : t00, u10 = A4 ? t10 : e2;
          u32 e3 = __shfl_xor(A4 ? t01 : t11, 16, 64);
          u32 u01 = A4 ? e3 : t01, u11 = A4 ? t11 : e3;
          union { u32 u[4]; bf16x8 v; } pbv;
          pbv.u[0] = u00; pbv.u[1] = u01; pbv.u[2] = u10; pbv.u[3] = u11;
          pb[g][ks] = pbv.v;
        }
      }

#pragma unroll
      for (int d = 0; d < 8; d++) {
        const int vrow = d * 16 + fr;
        const int sw = (vrow & 7) << 4;
#pragma unroll
        for (int ks = 0; ks < 2; ks++) {
          const int off = (vrow * 128 + ks * 64 + fq * 16) ^ sw;
          bf16x8 vf = *(const bf16x8*)((const char*)VsB + off);
          o[0][d] = __builtin_amdgcn_mfma_f32_16x16x32_bf16(vf, pb[0][ks], o[0][d], 0, 0, 0);
          o[1][d] = __builtin_amdgcn_mfma_f32_16x16x32_bf16(vf, pb[1][ks], o[1][d], 0, 0, 0);
        }
      }
      __builtin_amdgcn_s_barrier();
      cur ^= 1;
    }

#pragma unroll
    for (int g = 0; g < 2; g++) {
      const float inv = 1.f / lrow[g];
      const int qq = t * 32 + g * 16 + fr;
      u16* obase = AO + ((size_t)b * L + qq) * 4096 + h * 128 + fq * 4;
#pragma unroll
      for (int d = 0; d < 8; d++) {
        uint2 w;
        w.x = (u32)f2bf(o[g][d][0] * inv) | ((u32)f2bf(o[g][d][1] * inv) << 16);
        w.y = (u32)f2bf(o[g][d][2] * inv) | ((u32)f2bf(o[g][d][3] * inv) << 16);
        *(uint2*)(obase + d * 16) = w;
      }
    }
  }
}

// ---------------- launcher ----------------
extern "C" void kernel_launch(void* const* d_in, const int* in_sizes, int n_in,
                              void* d_out, int out_size, void* d_ws, size_t ws_size,
                              hipStream_t stream) {
  const float* x    = (const float*)d_in[0];
  const float* Wq   = (const float*)d_in[1];
  const float* Wk   = (const float*)d_in[2];
  const float* Wv   = (const float*)d_in[3];
  const float* Wo   = (const float*)d_in[4];
  const float* qw   = (const float*)d_in[5];
  const float* kw   = (const float*)d_in[6];
  const float* cosp = (const float*)d_in[7];
  const float* sinp = (const float*)d_in[8];
  float* out = (float*)d_out;
  char* ws = (char*)d_ws;

  u16* xb    = (u16*)(ws);                 // 4096x2560 bf16
  u16* WqkvT = (u16*)(ws + 20971520);      // 6144x2560 bf16
  u16* WoT   = (u16*)(ws + 52428800);      // 2560x4096 bf16
  u16* QKV   = (u16*)(ws + 73400320);      // 4096x6144 bf16
  u16* AO    = QKV;                        // alias: QKV dead before attn writes
  u16* Qrr   = (u16*)(ws + 123731968);
  u16* Krr   = (u16*)(ws + 157286400);
  u16* Vtt   = (u16*)(ws + 165675008);

  hipFuncSetAttribute(reinterpret_cast<const void*>(&gemmN<6, u16>),
                      hipFuncAttributeMaxDynamicSharedMemorySize, 131072);
  hipFuncSetAttribute(reinterpret_cast<const void*>(&gemmN<5, float>),
                      hipFuncAttributeMaxDynamicSharedMemorySize, 114688);

  cvt_f32_bf16<<<10240, 256, 0, stream>>>((const float4*)x, (uint2*)xb, 2621440);
  transpose_w<<<dim3(128, 80), 256, 0, stream>>>(Wq, WqkvT, 2560, 4096);
  transpose_w<<<dim3(32, 80), 256, 0, stream>>>(Wk, WqkvT + (size_t)4096 * 2560, 2560, 1024);
  transpose_w<<<dim3(32, 80), 256, 0, stream>>>(Wv, WqkvT + (size_t)5120 * 2560, 2560, 1024);
  transpose_w<<<dim3(80, 128), 256, 0, stream>>>(Wo, WoT, 4096, 2560);

  // QKV: M=4096 (32 tiles of 128), N=6144 (16 tiles of 384) -> 512 blocks
  gemmN<6, u16><<<512, 512, 131072, stream>>>(xb, WqkvT, QKV, 6144, 2560, 32);

  norm_rope<<<40960, 256, 0, stream>>>(QKV, qw, kw, cosp, sinp, Qrr, Krr);
  transpose_v<<<dim3(64, 4, 16), 256, 0, stream>>>(QKV, Vtt);

  attn_fwd<<<dim3(512), 256, 0, stream>>>(Qrr, Krr, Vtt, AO);

  // O-proj: M=4096 (32 tiles), N=2560 (8 tiles of 320) -> 256 blocks
  gemmN<5, float><<<256, 512, 114688, stream>>>(AO, WoT, out, 2560, 4096, 32);
}